// Round 2
// baseline (1154.297 us; speedup 1.0000x reference)
//
#include <hip/hip_runtime.h>
#include <math.h>

#define NN 50000
#define EE 400000
#define DD 256
#define HH 4
#define CC 64
#define LL 3
#define GG 25

// ---------------- GEMM: C[N][256] = A[N][256] @ B[256][256] (+bias) ----------------
#define BM 128
#define BN 128
#define BK 32

__global__ __launch_bounds__(256) void gemm_f32(
    const float* __restrict__ A, const float* __restrict__ B,
    const float* __restrict__ bias, float* __restrict__ C, int N)
{
  __shared__ float As[BK][BM + 4];   // transposed: As[k][m]
  __shared__ float Bs[BK][BN];
  const int t = threadIdx.x;
  const int bm = blockIdx.x * BM;
  const int bn = blockIdx.y * BN;
  const int tx = t & 15, ty = t >> 4;
  float acc[8][8];
#pragma unroll
  for (int i = 0; i < 8; i++)
#pragma unroll
    for (int j = 0; j < 8; j++) acc[i][j] = 0.f;

  for (int k0 = 0; k0 < DD; k0 += BK) {
    // A tile: 128 rows x 32 k  (1024 float4). f = i*256+t: row=f>>3, c4=f&7
#pragma unroll
    for (int i = 0; i < 4; i++) {
      int f = i * 256 + t;
      int ar = f >> 3;
      int ac4 = f & 7;
      int gr = bm + ar;
      float4 v = {0.f, 0.f, 0.f, 0.f};
      if (gr < N) v = *(const float4*)(A + (size_t)gr * DD + k0 + ac4 * 4);
      As[ac4 * 4 + 0][ar] = v.x;
      As[ac4 * 4 + 1][ar] = v.y;
      As[ac4 * 4 + 2][ar] = v.z;
      As[ac4 * 4 + 3][ar] = v.w;
    }
    // B tile: 32 rows x 128 cols (1024 float4). f = i*256+t: row=f>>5, c4=f&31
#pragma unroll
    for (int i = 0; i < 4; i++) {
      int f = i * 256 + t;
      int brr = f >> 5;
      int bc4 = f & 31;
      float4 v = *(const float4*)(B + (size_t)(k0 + brr) * DD + bn + bc4 * 4);
      *(float4*)(&Bs[brr][bc4 * 4]) = v;
    }
    __syncthreads();
#pragma unroll
    for (int kk = 0; kk < BK; kk++) {
      float a[8], b[8];
      *(float4*)&a[0] = *(const float4*)&As[kk][ty * 8];
      *(float4*)&a[4] = *(const float4*)&As[kk][ty * 8 + 4];
      *(float4*)&b[0] = *(const float4*)&Bs[kk][tx * 8];
      *(float4*)&b[4] = *(const float4*)&Bs[kk][tx * 8 + 4];
#pragma unroll
      for (int i = 0; i < 8; i++)
#pragma unroll
        for (int j = 0; j < 8; j++) acc[i][j] = fmaf(a[i], b[j], acc[i][j]);
    }
    __syncthreads();
  }
#pragma unroll
  for (int i = 0; i < 8; i++) {
    int r = bm + ty * 8 + i;
    if (r >= N) continue;
    float* cp = C + (size_t)r * DD + bn + tx * 8;
    float4 v0, v1;
    v0.x = acc[i][0]; v0.y = acc[i][1]; v0.z = acc[i][2]; v0.w = acc[i][3];
    v1.x = acc[i][4]; v1.y = acc[i][5]; v1.z = acc[i][6]; v1.w = acc[i][7];
    if (bias) {
      const float* bp = bias + bn + tx * 8;
      v0.x += bp[0]; v0.y += bp[1]; v0.z += bp[2]; v0.w += bp[3];
      v1.x += bp[4]; v1.y += bp[5]; v1.z += bp[6]; v1.w += bp[7];
    }
    *(float4*)cp = v0;
    *(float4*)(cp + 4) = v1;
  }
}

// ---------------- tiny precompute: fold attention vectors into W matrices ----------------
// wmat[l][k][0..3] = sum_c W_src[l][k][h*64+c]*att_src[l][h][c]
// wmat[l][k][4..7] = same with W_dst/att_dst
// wea[l][d][h]     = sum_c W_edge[l][d][h*64+c]*att_edge[l][h][c]
__global__ void prep_att(const float* __restrict__ Ws, const float* __restrict__ Wd,
                         const float* __restrict__ We, const float* __restrict__ as_,
                         const float* __restrict__ ad_, const float* __restrict__ ae_,
                         float* __restrict__ wmat, float* __restrict__ wea)
{
  int l = blockIdx.x;
  int t = threadIdx.x;
  for (int idx = t; idx < DD * 8; idx += 256) {
    int k = idx >> 3, hd = idx & 7;
    const float* W; const float* att; int hh;
    if (hd < 4) { W = Ws; att = as_; hh = hd; }
    else        { W = Wd; att = ad_; hh = hd - 4; }
    const float* wrow = W + (size_t)l * DD * DD + (size_t)k * DD + hh * CC;
    const float* arow = att + l * DD + hh * CC;
    float s = 0.f;
#pragma unroll 4
    for (int c = 0; c < CC; c++) s = fmaf(wrow[c], arow[c], s);
    wmat[(size_t)l * DD * 8 + idx] = s;
  }
  if (t < 8) {
    int d = t >> 2, hh = t & 3;
    const float* wrow = We + (size_t)l * 2 * DD + (size_t)d * DD + hh * CC;
    const float* arow = ae_ + l * DD + hh * CC;
    float s = 0.f;
#pragma unroll 4
    for (int c = 0; c < CC; c++) s = fmaf(wrow[c], arow[c], s);
    wea[l * 8 + d * 4 + hh] = s;
  }
}

// ---------------- graph boundaries (batch is sorted) ----------------
__global__ void graph_bounds(const int* __restrict__ batch, int* __restrict__ goff,
                             int N, int G)
{
  int g = threadIdx.x;
  if (g > G) return;
  int lo = 0, hi = N;
  while (lo < hi) { int mid = (lo + hi) >> 1; if (batch[mid] < g) lo = mid + 1; else hi = mid; }
  goff[g] = lo;
}

// ---------------- CSR build by destination ----------------
__global__ void hist_col(const int* __restrict__ ei, int* __restrict__ deg, int E)
{
  int e = blockIdx.x * 256 + threadIdx.x;
  if (e < E) atomicAdd(&deg[ei[E + e]], 1);
}

__global__ void scan1(const int* __restrict__ deg, int* __restrict__ incl,
                      int* __restrict__ bsum, int N)
{
  __shared__ int sm[256];
  int b = blockIdx.x, t = threadIdx.x;
  int i = b * 256 + t;
  int v = (i < N) ? deg[i] : 0;
  sm[t] = v;
  __syncthreads();
  for (int off = 1; off < 256; off <<= 1) {
    int add = (t >= off) ? sm[t - off] : 0;
    __syncthreads();
    sm[t] += add;
    __syncthreads();
  }
  if (i < N) incl[i] = sm[t];
  if (t == 255) bsum[b] = sm[255];
}

__global__ void scan2(int* __restrict__ bsum, int nb)
{
  if (threadIdx.x == 0 && blockIdx.x == 0) {
    int run = 0;
    for (int i = 0; i < nb; i++) { int v = bsum[i]; bsum[i] = run; run += v; }
  }
}

__global__ void scan3(const int* __restrict__ deg, const int* __restrict__ incl,
                      const int* __restrict__ bsum, int* __restrict__ rowptr,
                      int* __restrict__ cur, int N, int E)
{
  int i = blockIdx.x * 256 + threadIdx.x;
  if (i < N) {
    int ex = incl[i] - deg[i] + bsum[blockIdx.x];
    rowptr[i] = ex;
    cur[i] = ex;
  }
  if (i == 0) rowptr[N] = E;
}

__global__ void scatter_edges(const int* __restrict__ ei, const float* __restrict__ eattr,
                              int* __restrict__ cur, int* __restrict__ srow,
                              float2* __restrict__ sea, int E)
{
  int e = blockIdx.x * 256 + threadIdx.x;
  if (e < E) {
    int c = ei[E + e];
    int p = atomicAdd(&cur[c], 1);
    srow[p] = ei[e];
    sea[p] = ((const float2*)eattr)[e];
  }
}

// ---------------- per-node src/dst attention projections: [N,4] each ----------------
__global__ __launch_bounds__(256) void att_proj(
    const float* __restrict__ h, const float* __restrict__ wmatL,
    float* __restrict__ asrc, float* __restrict__ adst, int N)
{
  __shared__ float Hs[32][260];
  __shared__ float Wm[DD * 8];
  int t = threadIdx.x;
  for (int i = t; i < DD * 8; i += 256) Wm[i] = wmatL[i];
  int n0 = blockIdx.x * 32;
  for (int i = t; i < 32 * 64; i += 256) {
    int n = i >> 6, c4 = i & 63;
    float4 v = {0.f, 0.f, 0.f, 0.f};
    if (n0 + n < N) v = *(const float4*)(h + (size_t)(n0 + n) * DD + c4 * 4);
    Hs[n][c4 * 4 + 0] = v.x; Hs[n][c4 * 4 + 1] = v.y;
    Hs[n][c4 * 4 + 2] = v.z; Hs[n][c4 * 4 + 3] = v.w;
  }
  __syncthreads();
  int n = t >> 3, hd = t & 7;
  float s0 = 0, s1 = 0, s2 = 0, s3 = 0;
  for (int k = 0; k < DD; k += 4) {
    s0 = fmaf(Hs[n][k + 0], Wm[(k + 0) * 8 + hd], s0);
    s1 = fmaf(Hs[n][k + 1], Wm[(k + 1) * 8 + hd], s1);
    s2 = fmaf(Hs[n][k + 2], Wm[(k + 2) * 8 + hd], s2);
    s3 = fmaf(Hs[n][k + 3], Wm[(k + 3) * 8 + hd], s3);
  }
  float s = (s0 + s1) + (s2 + s3);
  int gn = n0 + n;
  if (gn < N) {
    if (hd < 4) asrc[gn * 4 + hd] = s;
    else        adst[gn * 4 + (hd - 4)] = s;
  }
}

// ---------------- fused per-destination kernel ----------------
// one wave per dst node: softmax (no atomics) + weighted message sum + bias + LN + PReLU + residual
__global__ __launch_bounds__(256) void dst_fused(
    const float* __restrict__ xs, const float* __restrict__ asrc,
    const float* __restrict__ adst, const int* __restrict__ rowptr,
    const int* __restrict__ srow, const float2* __restrict__ sea,
    const float* __restrict__ weaL, const float* __restrict__ biasL,
    const float* __restrict__ gL, const float* __restrict__ bL,
    const float* __restrict__ pL, float* __restrict__ h, int N)
{
  int wid = blockIdx.x * 4 + (threadIdx.x >> 6);
  int lane = threadIdx.x & 63;
  if (wid >= N) return;
  const int head = lane >> 4;              // dims d = 4*lane..4*lane+3, head = d/64
  const int start = rowptr[wid];
  const int end = rowptr[wid + 1];
  const float ad = adst[wid * 4 + head];
  const float w0 = weaL[head];
  const float w1 = weaL[4 + head];
  float ax = 0.f, ay = 0.f, az = 0.f, aw = 0.f;
  float z = 0.f;
  for (int p = start; p < end; ++p) {
    int r = srow[p];
    float2 ea = sea[p];
    float a = asrc[r * 4 + head] + ad + ea.x * w0 + ea.y * w1;
    a = a > 0.f ? a : 0.2f * a;            // leaky_relu(0.2)
    float w = expf(a);                     // segment-max skipped: |a| << 80
    z += w;
    float4 xv = *(const float4*)(xs + (size_t)r * DD + lane * 4);
    ax = fmaf(w, xv.x, ax); ay = fmaf(w, xv.y, ay);
    az = fmaf(w, xv.z, az); aw = fmaf(w, xv.w, aw);
  }
  float inv = 1.f / (z + 1e-16f);
  float4 bi = *(const float4*)(biasL + lane * 4);
  float o0 = ax * inv + bi.x;
  float o1 = ay * inv + bi.y;
  float o2 = az * inv + bi.z;
  float o3 = aw * inv + bi.w;
  float s = (o0 + o1) + (o2 + o3);
  float q = (o0 * o0 + o1 * o1) + (o2 * o2 + o3 * o3);
#pragma unroll
  for (int off = 32; off; off >>= 1) {
    s += __shfl_xor(s, off, 64);
    q += __shfl_xor(q, off, 64);
  }
  float mu = s * (1.f / 256.f);
  float var = q * (1.f / 256.f) - mu * mu;
  float rs = rsqrtf(var + 1e-5f);
  float4 gg = *(const float4*)(gL + lane * 4);
  float4 bb = *(const float4*)(bL + lane * 4);
  float4 pp = *(const float4*)(pL + lane * 4);
  o0 = (o0 - mu) * rs * gg.x + bb.x;  o0 = o0 > 0.f ? o0 : pp.x * o0;
  o1 = (o1 - mu) * rs * gg.y + bb.y;  o1 = o1 > 0.f ? o1 : pp.y * o1;
  o2 = (o2 - mu) * rs * gg.z + bb.z;  o2 = o2 > 0.f ? o2 : pp.z * o2;
  o3 = (o3 - mu) * rs * gg.w + bb.w;  o3 = o3 > 0.f ? o3 : pp.w * o3;
  float4 hv = *(const float4*)(h + (size_t)wid * DD + lane * 4);
  float4 ov;
  ov.x = o0 + hv.x; ov.y = o1 + hv.y; ov.z = o2 + hv.z; ov.w = o3 + hv.w;
  *(float4*)(h + (size_t)wid * DD + lane * 4) = ov;
}

// ---------------- per-graph mean (split blocks + few atomics) ----------------
__global__ void mean_accum(const float* __restrict__ x, const int* __restrict__ goff,
                           float* __restrict__ msum)
{
  int g = blockIdx.x, sp = blockIdx.y, t = threadIdx.x;
  int lo = goff[g], hi = goff[g + 1];
  int cnt = hi - lo;
  if (cnt <= 0) return;
  int per = (cnt + gridDim.y - 1) / gridDim.y;
  int st = lo + sp * per;
  int en = min(hi, st + per);
  if (st >= en) return;
  float acc = 0.f;
  for (int n = st; n < en; ++n) acc += x[(size_t)n * DD + t];
  atomicAdd(&msum[g * DD + t], acc);
}

__global__ void mean_fin(const float* __restrict__ msum, const int* __restrict__ goff,
                         float* __restrict__ dst)
{
  int g = blockIdx.x, t = threadIdx.x;
  int cnt = goff[g + 1] - goff[g];
  dst[g * DD + t] = msum[g * DD + t] / fmaxf((float)cnt, 1.f);
}

// ---------------- head MLP: [G,1024] -> relu 256 -> relu 256 -> 1 ----------------
__global__ __launch_bounds__(256) void head_mlp(
    const float* __restrict__ hmean, const float* __restrict__ W1,
    const float* __restrict__ b1, const float* __restrict__ W2,
    const float* __restrict__ b2, const float* __restrict__ Wr,
    const float* __restrict__ br, float* __restrict__ out)
{
  __shared__ float xc[4 * DD];
  __shared__ float p1[DD];
  __shared__ float red[256];
  int g = blockIdx.x, t = threadIdx.x;
  float m0 = hmean[0 * GG * DD + g * DD + t];
  float m1 = hmean[1 * GG * DD + g * DD + t];
  float m2 = hmean[2 * GG * DD + g * DD + t];
  float m3 = hmean[3 * GG * DD + g * DD + t];
  xc[t] = m0;               // mean(h0)
  xc[DD + t] = m1 - m0;     // mean(out_1)  (residual telescoping)
  xc[2 * DD + t] = m2 - m1;
  xc[3 * DD + t] = m3 - m2;
  __syncthreads();
  float acc = b1[t];
  for (int k = 0; k < 4 * DD; k++) acc = fmaf(xc[k], W1[(size_t)k * DD + t], acc);
  p1[t] = fmaxf(acc, 0.f);
  __syncthreads();
  float acc2 = b2[t];
  for (int k = 0; k < DD; k++) acc2 = fmaf(p1[k], W2[(size_t)k * DD + t], acc2);
  float v = fmaxf(acc2, 0.f) * Wr[t];
  red[t] = v;
  __syncthreads();
  for (int sdown = 128; sdown; sdown >>= 1) {
    if (t < sdown) red[t] += red[t + sdown];
    __syncthreads();
  }
  if (t == 0) out[g] = red[0] + br[0];
}

// ---------------- launch ----------------
extern "C" void kernel_launch(void* const* d_in, const int* in_sizes, int n_in,
                              void* d_out, int out_size, void* d_ws, size_t ws_size,
                              hipStream_t stream)
{
  const float* x        = (const float*)d_in[0];
  const float* eattr    = (const float*)d_in[1];
  const int*   eidx     = (const int*)d_in[2];
  const int*   batch    = (const int*)d_in[3];
  const float* W_pre    = (const float*)d_in[4];
  const float* b_pre    = (const float*)d_in[5];
  const float* W_src    = (const float*)d_in[6];
  const float* W_dst    = (const float*)d_in[7];
  const float* W_edge   = (const float*)d_in[8];
  const float* att_src  = (const float*)d_in[9];
  const float* att_dst  = (const float*)d_in[10];
  const float* att_edge = (const float*)d_in[11];
  const float* bias_conv= (const float*)d_in[12];
  const float* ln_g     = (const float*)d_in[13];
  const float* ln_b     = (const float*)d_in[14];
  const float* prelu    = (const float*)d_in[15];
  const float* W1       = (const float*)d_in[16];
  const float* b1       = (const float*)d_in[17];
  const float* W2       = (const float*)d_in[18];
  const float* b2       = (const float*)d_in[19];
  const float* Wr       = (const float*)d_in[20];
  const float* br       = (const float*)d_in[21];
  float* out = (float*)d_out;

  char* w = (char*)d_ws;
  size_t off = 0;
  auto alloc = [&](size_t bytes) -> char* {
    char* p = w + off;
    off += (bytes + 255) & ~(size_t)255;
    return p;
  };
  float*  h     = (float*)alloc((size_t)NN * DD * 4);
  float*  xs    = (float*)alloc((size_t)NN * DD * 4);
  float*  asrc  = (float*)alloc((size_t)NN * HH * 4);
  float*  adst  = (float*)alloc((size_t)NN * HH * 4);
  float*  wmat  = (float*)alloc((size_t)LL * DD * 8 * 4);
  float*  wea   = (float*)alloc((size_t)LL * 8 * 4);
  float*  hmean = (float*)alloc((size_t)(LL + 1) * GG * DD * 4);
  float*  msum  = (float*)alloc((size_t)GG * DD * 4);
  float2* sea   = (float2*)alloc((size_t)EE * 8);
  int*    goff  = (int*)alloc((GG + 1) * 4);
  int*    deg   = (int*)alloc((size_t)NN * 4);
  int*    rowptr= (int*)alloc((size_t)(NN + 1) * 4);
  int*    cur   = (int*)alloc((size_t)NN * 4);
  int*    incl  = (int*)alloc((size_t)NN * 4);
  int*    bsum  = (int*)alloc(256 * 4);
  int*    srow  = (int*)alloc((size_t)EE * 4);
  if (off > ws_size) return;  // workspace too small -> loud failure

  // small precomputes + CSR build (once; reused by all 3 layers)
  prep_att<<<dim3(LL), dim3(256), 0, stream>>>(W_src, W_dst, W_edge, att_src,
                                               att_dst, att_edge, wmat, wea);
  graph_bounds<<<dim3(1), dim3(32), 0, stream>>>(batch, goff, NN, GG);
  hipMemsetAsync(deg, 0, (size_t)NN * 4, stream);
  hist_col<<<dim3((EE + 255) / 256), dim3(256), 0, stream>>>(eidx, deg, EE);
  int nb = (NN + 255) / 256;
  scan1<<<dim3(nb), dim3(256), 0, stream>>>(deg, incl, bsum, NN);
  scan2<<<dim3(1), dim3(1), 0, stream>>>(bsum, nb);
  scan3<<<dim3(nb), dim3(256), 0, stream>>>(deg, incl, bsum, rowptr, cur, NN, EE);
  scatter_edges<<<dim3((EE + 255) / 256), dim3(256), 0, stream>>>(eidx, eattr, cur,
                                                                  srow, sea, EE);

  // h = x @ W_pre + b_pre
  dim3 gg((NN + BM - 1) / BM, DD / BN);
  gemm_f32<<<gg, dim3(256), 0, stream>>>(x, W_pre, b_pre, h, NN);
  hipMemsetAsync(msum, 0, (size_t)GG * DD * 4, stream);
  mean_accum<<<dim3(GG, 16), dim3(DD), 0, stream>>>(h, goff, msum);
  mean_fin<<<dim3(GG), dim3(DD), 0, stream>>>(msum, goff, hmean);

  for (int l = 0; l < LL; l++) {
    gemm_f32<<<gg, dim3(256), 0, stream>>>(h, W_src + (size_t)l * DD * DD,
                                           (const float*)nullptr, xs, NN);
    att_proj<<<dim3((NN + 31) / 32), dim3(256), 0, stream>>>(h, wmat + (size_t)l * DD * 8,
                                                             asrc, adst, NN);
    dst_fused<<<dim3((NN + 3) / 4), dim3(256), 0, stream>>>(
        xs, asrc, adst, rowptr, srow, sea, wea + l * 8, bias_conv + l * DD,
        ln_g + l * DD, ln_b + l * DD, prelu + l * DD, h, NN);
    hipMemsetAsync(msum, 0, (size_t)GG * DD * 4, stream);
    mean_accum<<<dim3(GG, 16), dim3(DD), 0, stream>>>(h, goff, msum);
    mean_fin<<<dim3(GG), dim3(DD), 0, stream>>>(msum, goff,
                                                hmean + (size_t)(l + 1) * GG * DD);
  }

  head_mlp<<<dim3(GG), dim3(256), 0, stream>>>(hmean, W1, b1, W2, b2, Wr, br, out);
}

// Round 5
// 982.365 us; speedup vs baseline: 1.1750x; 1.1750x over previous
//
#include <hip/hip_runtime.h>
#include <math.h>

#define NN 50000
#define NPAD 50048
#define EE 400000
#define DD 256
#define HH 4
#define CC 64
#define LL 3
#define GG 25

typedef _Float16 half4_t __attribute__((ext_vector_type(4)));
typedef _Float16 half8_t __attribute__((ext_vector_type(8)));
typedef float f32x4_t __attribute__((ext_vector_type(4)));

// ================= split-f16 MFMA GEMM =================
// C[N][256] = A[N][256] @ W[256][256] (+bias), A,W given as swizzled f16 hi/lo.
// Swizzle: element (r,k) stored at column k' = ((k>>3) ^ ((r>>1)&3))<<3 | (k&7).
// This makes both global_load_lds staging (linear) and ds_read_b128 fragment
// reads (2 lanes/bank) conflict-free.
__global__ __launch_bounds__(256) void gemm_mfma(
    const _Float16* __restrict__ Ahi, const _Float16* __restrict__ Alo,
    const _Float16* __restrict__ Bhi, const _Float16* __restrict__ Blo,
    const float* __restrict__ bias, float* __restrict__ C, int N)
{
  __shared__ _Float16 lds[4][128][32];   // Ahi, Alo, Bhi, Blo tiles (8 KB each)
  const int t = threadIdx.x;
  const int wave = t >> 6, lane = t & 63;
  const int m0 = blockIdx.x * 128, bn0 = blockIdx.y * 128;
  const int wm = wave >> 1, wn = wave & 1;

  f32x4_t acc[4][4];
#pragma unroll
  for (int i = 0; i < 4; i++)
#pragma unroll
    for (int j = 0; j < 4; j++) acc[i][j] = (f32x4_t){0.f, 0.f, 0.f, 0.f};

  const int l15 = lane & 15, kg = lane >> 4;
  int aoff[4], boff[4];
#pragma unroll
  for (int tr = 0; tr < 4; tr++) {
    int r = wm * 64 + tr * 16 + l15;
    aoff[tr] = r * 64 + ((kg ^ ((r >> 1) & 3)) * 16);
    int n = wn * 64 + tr * 16 + l15;
    boff[tr] = n * 64 + ((kg ^ ((n >> 1) & 3)) * 16);
  }

  const _Float16* gsrc[4];
  gsrc[0] = Ahi + (size_t)m0 * 256;
  gsrc[1] = Alo + (size_t)m0 * 256;
  gsrc[2] = Bhi + (size_t)bn0 * 256;
  gsrc[3] = Blo + (size_t)bn0 * 256;

  const char* lbase = (const char*)&lds[0][0][0];

  for (int k0 = 0; k0 < DD; k0 += 32) {
    __syncthreads();                       // LDS safe to overwrite
#pragma unroll
    for (int b = 0; b < 4; b++) {
#pragma unroll
      for (int c = 0; c < 2; c++) {
        int rowbase = (wave << 5) + (c << 4);
        const _Float16* g = gsrc[b] + (size_t)(rowbase + (lane >> 2)) * 256
                            + k0 + (lane & 3) * 8;
        char* l = (char*)lbase + b * 8192 + rowbase * 64;
        __builtin_amdgcn_global_load_lds(
            (const __attribute__((address_space(1))) void*)g,
            (__attribute__((address_space(3))) void*)l, 16, 0, 0);
      }
    }
    __syncthreads();                       // drains vmcnt -> tiles ready

    half8_t ah[4], al[4], bh[4], bl[4];
#pragma unroll
    for (int i = 0; i < 4; i++) {
      ah[i] = *(const half8_t*)(lbase + 0 * 8192 + aoff[i]);
      al[i] = *(const half8_t*)(lbase + 1 * 8192 + aoff[i]);
      bh[i] = *(const half8_t*)(lbase + 2 * 8192 + boff[i]);
      bl[i] = *(const half8_t*)(lbase + 3 * 8192 + boff[i]);
    }
#pragma unroll
    for (int i = 0; i < 4; i++)
#pragma unroll
      for (int j = 0; j < 4; j++) {
        acc[i][j] = __builtin_amdgcn_mfma_f32_16x16x32_f16(ah[i], bh[j], acc[i][j], 0, 0, 0);
        acc[i][j] = __builtin_amdgcn_mfma_f32_16x16x32_f16(ah[i], bl[j], acc[i][j], 0, 0, 0);
        acc[i][j] = __builtin_amdgcn_mfma_f32_16x16x32_f16(al[i], bh[j], acc[i][j], 0, 0, 0);
      }
  }

#pragma unroll
  for (int i = 0; i < 4; i++) {
    int rb = m0 + wm * 64 + i * 16 + (lane >> 4) * 4;
#pragma unroll
    for (int j = 0; j < 4; j++) {
      int col = bn0 + wn * 64 + j * 16 + l15;
      float bv = bias ? bias[col] : 0.f;
#pragma unroll
      for (int q = 0; q < 4; q++) {
        int r = rb + q;
        if (r < N) C[(size_t)r * DD + col] = acc[i][j][q] + bv;
      }
    }
  }
}

// ---------------- f32 -> swizzled f16 hi/lo split ----------------
__global__ __launch_bounds__(256) void split_f16(
    const float* __restrict__ src, _Float16* __restrict__ hi,
    _Float16* __restrict__ lo, int N)
{
  int f = blockIdx.x * 256 + threadIdx.x;    // float4 index
  if (f >= N * 64) return;
  int m = f >> 6, q = f & 63;
  float4 v = *(const float4*)(src + (size_t)f * 4);
  int gp = (q >> 1) ^ ((m >> 1) & 3);
  int off = m * 256 + gp * 8 + (q & 1) * 4;
  half4_t h4, l4;
  h4[0] = (_Float16)v.x; l4[0] = (_Float16)(v.x - (float)h4[0]);
  h4[1] = (_Float16)v.y; l4[1] = (_Float16)(v.y - (float)h4[1]);
  h4[2] = (_Float16)v.z; l4[2] = (_Float16)(v.z - (float)h4[2]);
  h4[3] = (_Float16)v.w; l4[3] = (_Float16)(v.w - (float)h4[3]);
  *(half4_t*)(hi + off) = h4;
  *(half4_t*)(lo + off) = l4;
}

// ---------------- W[256][256] -> transposed swizzled f16 hi/lo ----------------
__global__ void prep_w(const float* __restrict__ W, _Float16* __restrict__ bhi,
                       _Float16* __restrict__ blo)
{
  int n = blockIdx.x, k = threadIdx.x;
  float v = W[(size_t)k * DD + n];
  _Float16 h = (_Float16)v, l = (_Float16)(v - (float)h);
  int kp = (((k >> 3) ^ ((n >> 1) & 3)) << 3) | (k & 7);
  bhi[(size_t)n * DD + kp] = h;
  blo[(size_t)n * DD + kp] = l;
}

// ---------------- fold attention vectors into W matrices ----------------
__global__ void prep_att(const float* __restrict__ Ws, const float* __restrict__ Wd,
                         const float* __restrict__ We, const float* __restrict__ as_,
                         const float* __restrict__ ad_, const float* __restrict__ ae_,
                         float* __restrict__ wmat, float* __restrict__ wea)
{
  int l = blockIdx.x;
  int t = threadIdx.x;
  for (int idx = t; idx < DD * 8; idx += 256) {
    int k = idx >> 3, hd = idx & 7;
    const float* W; const float* att; int hh;
    if (hd < 4) { W = Ws; att = as_; hh = hd; }
    else        { W = Wd; att = ad_; hh = hd - 4; }
    const float* wrow = W + (size_t)l * DD * DD + (size_t)k * DD + hh * CC;
    const float* arow = att + l * DD + hh * CC;
    float s = 0.f;
#pragma unroll 4
    for (int c = 0; c < CC; c++) s = fmaf(wrow[c], arow[c], s);
    wmat[(size_t)l * DD * 8 + idx] = s;
  }
  if (t < 8) {
    int d = t >> 2, hh = t & 3;
    const float* wrow = We + (size_t)l * 2 * DD + (size_t)d * DD + hh * CC;
    const float* arow = ae_ + l * DD + hh * CC;
    float s = 0.f;
#pragma unroll 4
    for (int c = 0; c < CC; c++) s = fmaf(wrow[c], arow[c], s);
    wea[l * 8 + d * 4 + hh] = s;
  }
}

// ---------------- graph boundaries ----------------
__global__ void graph_bounds(const int* __restrict__ batch, int* __restrict__ goff,
                             int N, int G)
{
  int g = threadIdx.x;
  if (g > G) return;
  int lo = 0, hi = N;
  while (lo < hi) { int mid = (lo + hi) >> 1; if (batch[mid] < g) lo = mid + 1; else hi = mid; }
  goff[g] = lo;
}

// ---------------- CSR build by destination ----------------
__global__ void hist_col(const int* __restrict__ ei, int* __restrict__ deg, int E)
{
  int e = blockIdx.x * 256 + threadIdx.x;
  if (e < E) atomicAdd(&deg[ei[E + e]], 1);
}

__global__ void scan1(const int* __restrict__ deg, int* __restrict__ incl,
                      int* __restrict__ bsum, int N)
{
  __shared__ int sm[256];
  int b = blockIdx.x, t = threadIdx.x;
  int i = b * 256 + t;
  int v = (i < N) ? deg[i] : 0;
  sm[t] = v;
  __syncthreads();
  for (int off = 1; off < 256; off <<= 1) {
    int add = (t >= off) ? sm[t - off] : 0;
    __syncthreads();
    sm[t] += add;
    __syncthreads();
  }
  if (i < N) incl[i] = sm[t];
  if (t == 255) bsum[b] = sm[255];
}

__global__ void scan2(int* __restrict__ bsum, int nb)
{
  if (threadIdx.x == 0 && blockIdx.x == 0) {
    int run = 0;
    for (int i = 0; i < nb; i++) { int v = bsum[i]; bsum[i] = run; run += v; }
  }
}

__global__ void scan3(const int* __restrict__ deg, const int* __restrict__ incl,
                      const int* __restrict__ bsum, int* __restrict__ rowptr,
                      int* __restrict__ cur, int N, int E)
{
  int i = blockIdx.x * 256 + threadIdx.x;
  if (i < N) {
    int ex = incl[i] - deg[i] + bsum[blockIdx.x];
    rowptr[i] = ex;
    cur[i] = ex;
  }
  if (i == 0) rowptr[N] = E;
}

__global__ void scatter_edges(const int* __restrict__ ei, const float* __restrict__ eattr,
                              int* __restrict__ cur, int* __restrict__ srow,
                              float2* __restrict__ sea, int E)
{
  int e = blockIdx.x * 256 + threadIdx.x;
  if (e < E) {
    int c = ei[E + e];
    int p = atomicAdd(&cur[c], 1);
    srow[p] = ei[e];
    sea[p] = ((const float2*)eattr)[e];
  }
}

// ---------------- per-node src/dst attention projections ----------------
__global__ __launch_bounds__(256) void att_proj(
    const float* __restrict__ h, const float* __restrict__ wmatL,
    float* __restrict__ asrc, float* __restrict__ adst, int N)
{
  __shared__ float Hs[32][260];
  __shared__ float Wm[DD * 8];
  int t = threadIdx.x;
  for (int i = t; i < DD * 8; i += 256) Wm[i] = wmatL[i];
  int n0 = blockIdx.x * 32;
  for (int i = t; i < 32 * 64; i += 256) {
    int n = i >> 6, c4 = i & 63;
    float4 v = {0.f, 0.f, 0.f, 0.f};
    if (n0 + n < N) v = *(const float4*)(h + (size_t)(n0 + n) * DD + c4 * 4);
    Hs[n][c4 * 4 + 0] = v.x; Hs[n][c4 * 4 + 1] = v.y;
    Hs[n][c4 * 4 + 2] = v.z; Hs[n][c4 * 4 + 3] = v.w;
  }
  __syncthreads();
  int n = t >> 3, hd = t & 7;
  float s0 = 0, s1 = 0, s2 = 0, s3 = 0;
  for (int k = 0; k < DD; k += 4) {
    s0 = fmaf(Hs[n][k + 0], Wm[(k + 0) * 8 + hd], s0);
    s1 = fmaf(Hs[n][k + 1], Wm[(k + 1) * 8 + hd], s1);
    s2 = fmaf(Hs[n][k + 2], Wm[(k + 2) * 8 + hd], s2);
    s3 = fmaf(Hs[n][k + 3], Wm[(k + 3) * 8 + hd], s3);
  }
  float s = (s0 + s1) + (s2 + s3);
  int gn = n0 + n;
  if (gn < N) {
    if (hd < 4) asrc[gn * 4 + hd] = s;
    else        adst[gn * 4 + (hd - 4)] = s;
  }
}

// ---------------- fused per-destination kernel ----------------
__global__ __launch_bounds__(256) void dst_fused(
    const float* __restrict__ xs, const float* __restrict__ asrc,
    const float* __restrict__ adst, const int* __restrict__ rowptr,
    const int* __restrict__ srow, const float2* __restrict__ sea,
    const float* __restrict__ weaL, const float* __restrict__ biasL,
    const float* __restrict__ gL, const float* __restrict__ bL,
    const float* __restrict__ pL, float* __restrict__ h,
    _Float16* __restrict__ hhi, _Float16* __restrict__ hlo, int N)
{
  int wid = blockIdx.x * 4 + (threadIdx.x >> 6);
  int lane = threadIdx.x & 63;
  if (wid >= N) return;
  const int head = lane >> 4;
  const int start = rowptr[wid];
  const int end = rowptr[wid + 1];
  const float ad = adst[wid * 4 + head];
  const float w0 = weaL[head];
  const float w1 = weaL[4 + head];
  float ax = 0.f, ay = 0.f, az = 0.f, aw = 0.f;
  float z = 0.f;
  int p = start;
  for (; p + 2 <= end; p += 2) {           // 2x unroll: overlap gather latency
    int r0 = srow[p], r1 = srow[p + 1];
    float2 e0 = sea[p], e1 = sea[p + 1];
    float s0 = asrc[r0 * 4 + head], s1 = asrc[r1 * 4 + head];
    float4 x0 = *(const float4*)(xs + (size_t)r0 * DD + lane * 4);
    float4 x1 = *(const float4*)(xs + (size_t)r1 * DD + lane * 4);
    float a0 = s0 + ad + e0.x * w0 + e0.y * w1;
    a0 = a0 > 0.f ? a0 : 0.2f * a0;
    float wt0 = expf(a0);
    float a1 = s1 + ad + e1.x * w0 + e1.y * w1;
    a1 = a1 > 0.f ? a1 : 0.2f * a1;
    float wt1 = expf(a1);
    z += wt0 + wt1;
    ax = fmaf(wt0, x0.x, ax); ay = fmaf(wt0, x0.y, ay);
    az = fmaf(wt0, x0.z, az); aw = fmaf(wt0, x0.w, aw);
    ax = fmaf(wt1, x1.x, ax); ay = fmaf(wt1, x1.y, ay);
    az = fmaf(wt1, x1.z, az); aw = fmaf(wt1, x1.w, aw);
  }
  if (p < end) {
    int r = srow[p];
    float2 ea = sea[p];
    float a = asrc[r * 4 + head] + ad + ea.x * w0 + ea.y * w1;
    a = a > 0.f ? a : 0.2f * a;
    float wt = expf(a);
    z += wt;
    float4 xv = *(const float4*)(xs + (size_t)r * DD + lane * 4);
    ax = fmaf(wt, xv.x, ax); ay = fmaf(wt, xv.y, ay);
    az = fmaf(wt, xv.z, az); aw = fmaf(wt, xv.w, aw);
  }
  float inv = 1.f / (z + 1e-16f);
  float4 bi = *(const float4*)(biasL + lane * 4);
  float o0 = ax * inv + bi.x;
  float o1 = ay * inv + bi.y;
  float o2 = az * inv + bi.z;
  float o3 = aw * inv + bi.w;
  float s = (o0 + o1) + (o2 + o3);
  float q = (o0 * o0 + o1 * o1) + (o2 * o2 + o3 * o3);
#pragma unroll
  for (int off = 32; off; off >>= 1) {
    s += __shfl_xor(s, off, 64);
    q += __shfl_xor(q, off, 64);
  }
  float mu = s * (1.f / 256.f);
  float var = q * (1.f / 256.f) - mu * mu;
  float rs = rsqrtf(var + 1e-5f);
  float4 gg = *(const float4*)(gL + lane * 4);
  float4 bb = *(const float4*)(bL + lane * 4);
  float4 pp = *(const float4*)(pL + lane * 4);
  o0 = (o0 - mu) * rs * gg.x + bb.x;  o0 = o0 > 0.f ? o0 : pp.x * o0;
  o1 = (o1 - mu) * rs * gg.y + bb.y;  o1 = o1 > 0.f ? o1 : pp.y * o1;
  o2 = (o2 - mu) * rs * gg.z + bb.z;  o2 = o2 > 0.f ? o2 : pp.z * o2;
  o3 = (o3 - mu) * rs * gg.w + bb.w;  o3 = o3 > 0.f ? o3 : pp.w * o3;
  float4 hv = *(const float4*)(h + (size_t)wid * DD + lane * 4);
  float4 ov;
  ov.x = o0 + hv.x; ov.y = o1 + hv.y; ov.z = o2 + hv.z; ov.w = o3 + hv.w;
  *(float4*)(h + (size_t)wid * DD + lane * 4) = ov;
  if (hhi) {                                  // fused split for next layer's GEMM
    int gp = (lane >> 1) ^ ((wid >> 1) & 3);
    int off2 = wid * DD + gp * 8 + (lane & 1) * 4;
    half4_t h4, l4;
    h4[0] = (_Float16)ov.x; l4[0] = (_Float16)(ov.x - (float)h4[0]);
    h4[1] = (_Float16)ov.y; l4[1] = (_Float16)(ov.y - (float)h4[1]);
    h4[2] = (_Float16)ov.z; l4[2] = (_Float16)(ov.z - (float)h4[2]);
    h4[3] = (_Float16)ov.w; l4[3] = (_Float16)(ov.w - (float)h4[3]);
    *(half4_t*)(hhi + off2) = h4;
    *(half4_t*)(hlo + off2) = l4;
  }
}

// ---------------- per-graph mean ----------------
__global__ void mean_accum(const float* __restrict__ x, const int* __restrict__ goff,
                           float* __restrict__ msum)
{
  int g = blockIdx.x, sp = blockIdx.y, t = threadIdx.x;
  int lo = goff[g], hi = goff[g + 1];
  int cnt = hi - lo;
  if (cnt <= 0) return;
  int per = (cnt + gridDim.y - 1) / gridDim.y;
  int st = lo + sp * per;
  int en = min(hi, st + per);
  if (st >= en) return;
  float acc = 0.f;
  for (int n = st; n < en; ++n) acc += x[(size_t)n * DD + t];
  atomicAdd(&msum[g * DD + t], acc);
}

__global__ void mean_fin(const float* __restrict__ msum, const int* __restrict__ goff,
                         float* __restrict__ dst)
{
  int g = blockIdx.x, t = threadIdx.x;
  int cnt = goff[g + 1] - goff[g];
  dst[g * DD + t] = msum[g * DD + t] / fmaxf((float)cnt, 1.f);
}

// ---------------- head MLP ----------------
__global__ __launch_bounds__(256) void head_mlp(
    const float* __restrict__ hmean, const float* __restrict__ W1,
    const float* __restrict__ b1, const float* __restrict__ W2,
    const float* __restrict__ b2, const float* __restrict__ Wr,
    const float* __restrict__ br, float* __restrict__ out)
{
  __shared__ float xc[4 * DD];
  __shared__ float p1[DD];
  __shared__ float red[256];
  int g = blockIdx.x, t = threadIdx.x;
  float m0 = hmean[0 * GG * DD + g * DD + t];
  float m1 = hmean[1 * GG * DD + g * DD + t];
  float m2 = hmean[2 * GG * DD + g * DD + t];
  float m3 = hmean[3 * GG * DD + g * DD + t];
  xc[t] = m0;
  xc[DD + t] = m1 - m0;
  xc[2 * DD + t] = m2 - m1;
  xc[3 * DD + t] = m3 - m2;
  __syncthreads();
  float acc = b1[t];
  for (int k = 0; k < 4 * DD; k++) acc = fmaf(xc[k], W1[(size_t)k * DD + t], acc);
  p1[t] = fmaxf(acc, 0.f);
  __syncthreads();
  float acc2 = b2[t];
  for (int k = 0; k < DD; k++) acc2 = fmaf(p1[k], W2[(size_t)k * DD + t], acc2);
  float v = fmaxf(acc2, 0.f) * Wr[t];
  red[t] = v;
  __syncthreads();
  for (int sdown = 128; sdown; sdown >>= 1) {
    if (t < sdown) red[t] += red[t + sdown];
    __syncthreads();
  }
  if (t == 0) out[g] = red[0] + br[0];
}

// ---------------- launch ----------------
extern "C" void kernel_launch(void* const* d_in, const int* in_sizes, int n_in,
                              void* d_out, int out_size, void* d_ws, size_t ws_size,
                              hipStream_t stream)
{
  const float* x        = (const float*)d_in[0];
  const float* eattr    = (const float*)d_in[1];
  const int*   eidx     = (const int*)d_in[2];
  const int*   batch    = (const int*)d_in[3];
  const float* W_pre    = (const float*)d_in[4];
  const float* b_pre    = (const float*)d_in[5];
  const float* W_src    = (const float*)d_in[6];
  const float* W_dst    = (const float*)d_in[7];
  const float* W_edge   = (const float*)d_in[8];
  const float* att_src  = (const float*)d_in[9];
  const float* att_dst  = (const float*)d_in[10];
  const float* att_edge = (const float*)d_in[11];
  const float* bias_conv= (const float*)d_in[12];
  const float* ln_g     = (const float*)d_in[13];
  const float* ln_b     = (const float*)d_in[14];
  const float* prelu    = (const float*)d_in[15];
  const float* W1       = (const float*)d_in[16];
  const float* b1       = (const float*)d_in[17];
  const float* W2       = (const float*)d_in[18];
  const float* b2       = (const float*)d_in[19];
  const float* Wr       = (const float*)d_in[20];
  const float* br       = (const float*)d_in[21];
  float* out = (float*)d_out;

  char* w = (char*)d_ws;
  size_t off = 0;
  auto alloc = [&](size_t bytes) -> char* {
    char* p = w + off;
    off += (bytes + 255) & ~(size_t)255;
    return p;
  };
  float*     h     = (float*)alloc((size_t)NN * DD * 4);
  char*      xsreg = alloc((size_t)NPAD * DD * 4);     // xs f32  |  x_hi + x_lo alias
  float*     xs    = (float*)xsreg;
  _Float16*  x_hi  = (_Float16*)xsreg;
  _Float16*  x_lo  = (_Float16*)(xsreg + (size_t)NPAD * DD * 2);
  _Float16*  h_hi  = (_Float16*)alloc((size_t)NPAD * DD * 2);
  _Float16*  h_lo  = (_Float16*)alloc((size_t)NPAD * DD * 2);
  _Float16*  bt_hi = (_Float16*)alloc((size_t)4 * DD * DD * 2);  // W_pre, W_src[0..2]
  _Float16*  bt_lo = (_Float16*)alloc((size_t)4 * DD * DD * 2);
  float*  asrc  = (float*)alloc((size_t)NN * HH * 4);
  float*  adst  = (float*)alloc((size_t)NN * HH * 4);
  float*  wmat  = (float*)alloc((size_t)LL * DD * 8 * 4);
  float*  wea   = (float*)alloc((size_t)LL * 8 * 4);
  float*  hmean = (float*)alloc((size_t)(LL + 1) * GG * DD * 4);
  float*  msum  = (float*)alloc((size_t)GG * DD * 4);
  float2* sea   = (float2*)alloc((size_t)EE * 8);
  int*    goff  = (int*)alloc((GG + 1) * 4);
  int*    deg   = (int*)alloc((size_t)NN * 4);
  int*    rowptr= (int*)alloc((size_t)(NN + 1) * 4);
  int*    cur   = (int*)alloc((size_t)NN * 4);
  int*    incl  = (int*)alloc((size_t)NN * 4);
  int*    bsum  = (int*)alloc(256 * 4);
  int*    srow  = (int*)alloc((size_t)EE * 4);
  if (off > ws_size) return;

  // precomputes + CSR build
  prep_att<<<dim3(LL), dim3(256), 0, stream>>>(W_src, W_dst, W_edge, att_src,
                                               att_dst, att_edge, wmat, wea);
  prep_w<<<dim3(DD), dim3(DD), 0, stream>>>(W_pre, bt_hi, bt_lo);
  for (int l = 0; l < LL; l++)
    prep_w<<<dim3(DD), dim3(DD), 0, stream>>>(W_src + (size_t)l * DD * DD,
                                              bt_hi + (size_t)(l + 1) * DD * DD,
                                              bt_lo + (size_t)(l + 1) * DD * DD);
  graph_bounds<<<dim3(1), dim3(32), 0, stream>>>(batch, goff, NN, GG);
  hipMemsetAsync(deg, 0, (size_t)NN * 4, stream);
  hist_col<<<dim3((EE + 255) / 256), dim3(256), 0, stream>>>(eidx, deg, EE);
  int nb = (NN + 255) / 256;
  scan1<<<dim3(nb), dim3(256), 0, stream>>>(deg, incl, bsum, NN);
  scan2<<<dim3(1), dim3(1), 0, stream>>>(bsum, nb);
  scan3<<<dim3(nb), dim3(256), 0, stream>>>(deg, incl, bsum, rowptr, cur, NN, EE);
  scatter_edges<<<dim3((EE + 255) / 256), dim3(256), 0, stream>>>(eidx, eattr, cur,
                                                                  srow, sea, EE);

  // h = x @ W_pre + b_pre  (via f16 split MFMA)
  split_f16<<<dim3((NN * 64 + 255) / 256), dim3(256), 0, stream>>>(x, x_hi, x_lo, NN);
  dim3 gg((NN + 127) / 128, 2);
  gemm_mfma<<<gg, dim3(256), 0, stream>>>(x_hi, x_lo, bt_hi, bt_lo, b_pre, h, NN);
  split_f16<<<dim3((NN * 64 + 255) / 256), dim3(256), 0, stream>>>(h, h_hi, h_lo, NN);
  hipMemsetAsync(msum, 0, (size_t)GG * DD * 4, stream);
  mean_accum<<<dim3(GG, 16), dim3(DD), 0, stream>>>(h, goff, msum);
  mean_fin<<<dim3(GG), dim3(DD), 0, stream>>>(msum, goff, hmean);

  for (int l = 0; l < LL; l++) {
    gemm_mfma<<<gg, dim3(256), 0, stream>>>(h_hi, h_lo,
                                            bt_hi + (size_t)(l + 1) * DD * DD,
                                            bt_lo + (size_t)(l + 1) * DD * DD,
                                            (const float*)nullptr, xs, NN);
    att_proj<<<dim3((NN + 31) / 32), dim3(256), 0, stream>>>(h, wmat + (size_t)l * DD * 8,
                                                             asrc, adst, NN);
    bool ws = (l < LL - 1);
    dst_fused<<<dim3((NN + 3) / 4), dim3(256), 0, stream>>>(
        xs, asrc, adst, rowptr, srow, sea, wea + l * 8, bias_conv + l * DD,
        ln_g + l * DD, ln_b + l * DD, prelu + l * DD, h,
        ws ? h_hi : (_Float16*)nullptr, ws ? h_lo : (_Float16*)nullptr, NN);
    hipMemsetAsync(msum, 0, (size_t)GG * DD * 4, stream);
    mean_accum<<<dim3(GG, 16), dim3(DD), 0, stream>>>(h, goff, msum);
    mean_fin<<<dim3(GG), dim3(DD), 0, stream>>>(msum, goff,
                                                hmean + (size_t)(l + 1) * GG * DD);
  }

  head_mlp<<<dim3(GG), dim3(256), 0, stream>>>(hmean, W1, b1, W2, b2, Wr, br, out);
}

// Round 7
// 935.702 us; speedup vs baseline: 1.2336x; 1.0499x over previous
//
#include <hip/hip_runtime.h>
#include <math.h>

#define NN 50000
#define NPAD 50048
#define EE 400000
#define DD 256
#define HH 4
#define CC 64
#define LL 3
#define GG 25

typedef _Float16 half4_t __attribute__((ext_vector_type(4)));
typedef _Float16 half8_t __attribute__((ext_vector_type(8)));
typedef float f32x4_t __attribute__((ext_vector_type(4)));

// ================= split-f16 MFMA GEMM, 2-phase double-buffered =================
// C[N][256] = A[N][256] @ W[256][256] (+bias). A,W as swizzled f16 hi/lo.
// Swizzle: element (r,k) at column k' = ((k>>3) ^ ((r>>1)&3))<<3 | (k&7).
__global__ __launch_bounds__(256) void gemm_mfma(
    const _Float16* __restrict__ Ahi, const _Float16* __restrict__ Alo,
    const _Float16* __restrict__ Bhi, const _Float16* __restrict__ Blo,
    const float* __restrict__ bias, float* __restrict__ C, int N)
{
  __shared__ _Float16 lds[2][4][128][32];   // 2 bufs x {Ahi,Alo,Bhi,Blo} = 64 KB
  const int t = threadIdx.x;
  const int wave = t >> 6, lane = t & 63;
  const int m0 = blockIdx.x * 128, bn0 = blockIdx.y * 128;
  const int wm = wave >> 1, wn = wave & 1;

  f32x4_t acc[4][4];
#pragma unroll
  for (int i = 0; i < 4; i++)
#pragma unroll
    for (int j = 0; j < 4; j++) acc[i][j] = (f32x4_t){0.f, 0.f, 0.f, 0.f};

  const int l15 = lane & 15, kg = lane >> 4;
  int aoff[4], boff[4];
#pragma unroll
  for (int tr = 0; tr < 4; tr++) {
    int r = wm * 64 + tr * 16 + l15;
    aoff[tr] = r * 64 + ((kg ^ ((r >> 1) & 3)) * 16);
    int n = wn * 64 + tr * 16 + l15;
    boff[tr] = n * 64 + ((kg ^ ((n >> 1) & 3)) * 16);
  }

  const _Float16* gsrc[4];
  gsrc[0] = Ahi + (size_t)m0 * 256;
  gsrc[1] = Alo + (size_t)m0 * 256;
  gsrc[2] = Bhi + (size_t)bn0 * 256;
  gsrc[3] = Blo + (size_t)bn0 * 256;

  char* lbase = (char*)&lds[0][0][0][0];
  const int rowbase0 = (wave << 5);

  auto stage = [&](int buf, int k0) {
#pragma unroll
    for (int b = 0; b < 4; b++) {
#pragma unroll
      for (int c = 0; c < 2; c++) {
        int rowbase = rowbase0 + (c << 4);
        const _Float16* g = gsrc[b] + (size_t)(rowbase + (lane >> 2)) * 256
                            + k0 + (lane & 3) * 8;
        char* l = lbase + (size_t)(buf * 4 + b) * 8192 + rowbase * 64;
        __builtin_amdgcn_global_load_lds(
            (const __attribute__((address_space(1))) void*)g,
            (__attribute__((address_space(3))) void*)l, 16, 0, 0);
      }
    }
  };

  stage(0, 0);
  __syncthreads();                         // prologue drain: buf0 ready
  int cur = 0;
  for (int k0 = 0; k0 < DD; k0 += 32) {
    if (k0 + 32 < DD) stage(cur ^ 1, k0 + 32);   // prefetch next tile (in flight)

    const char* lb = lbase + (size_t)cur * 4 * 8192;
    half8_t ah[4], al[4], bh[4], bl[4];
#pragma unroll
    for (int i = 0; i < 4; i++) {
      ah[i] = *(const half8_t*)(lb + 0 * 8192 + aoff[i]);
      al[i] = *(const half8_t*)(lb + 1 * 8192 + aoff[i]);
      bh[i] = *(const half8_t*)(lb + 2 * 8192 + boff[i]);
      bl[i] = *(const half8_t*)(lb + 3 * 8192 + boff[i]);
    }
#pragma unroll
    for (int i = 0; i < 4; i++)
#pragma unroll
      for (int j = 0; j < 4; j++) {
        acc[i][j] = __builtin_amdgcn_mfma_f32_16x16x32_f16(ah[i], bh[j], acc[i][j], 0, 0, 0);
        acc[i][j] = __builtin_amdgcn_mfma_f32_16x16x32_f16(ah[i], bl[j], acc[i][j], 0, 0, 0);
        acc[i][j] = __builtin_amdgcn_mfma_f32_16x16x32_f16(al[i], bh[j], acc[i][j], 0, 0, 0);
      }
    __syncthreads();                       // drains next-tile vmcnt + barrier
    cur ^= 1;
  }

#pragma unroll
  for (int i = 0; i < 4; i++) {
    int rb = m0 + wm * 64 + i * 16 + (lane >> 4) * 4;
#pragma unroll
    for (int j = 0; j < 4; j++) {
      int col = bn0 + wn * 64 + j * 16 + l15;
      float bv = bias ? bias[col] : 0.f;
#pragma unroll
      for (int q = 0; q < 4; q++) {
        int r = rb + q;
        if (r < N) C[(size_t)r * DD + col] = acc[i][j][q] + bv;
      }
    }
  }
}

// ---------------- f32 -> swizzled f16 hi/lo split ----------------
__global__ __launch_bounds__(256) void split_f16(
    const float* __restrict__ src, _Float16* __restrict__ hi,
    _Float16* __restrict__ lo, int N)
{
  int f = blockIdx.x * 256 + threadIdx.x;    // float4 index
  if (f >= N * 64) return;
  int m = f >> 6, q = f & 63;
  float4 v = *(const float4*)(src + (size_t)f * 4);
  int gp = (q >> 1) ^ ((m >> 1) & 3);
  int off = m * 256 + gp * 8 + (q & 1) * 4;
  half4_t h4, l4;
  h4[0] = (_Float16)v.x; l4[0] = (_Float16)(v.x - (float)h4[0]);
  h4[1] = (_Float16)v.y; l4[1] = (_Float16)(v.y - (float)h4[1]);
  h4[2] = (_Float16)v.z; l4[2] = (_Float16)(v.z - (float)h4[2]);
  h4[3] = (_Float16)v.w; l4[3] = (_Float16)(v.w - (float)h4[3]);
  *(half4_t*)(hi + off) = h4;
  *(half4_t*)(lo + off) = l4;
}

// ---------------- W[256][256] -> transposed swizzled f16 hi/lo ----------------
__global__ void prep_w(const float* __restrict__ W, _Float16* __restrict__ bhi,
                       _Float16* __restrict__ blo)
{
  int n = blockIdx.x, k = threadIdx.x;
  float v = W[(size_t)k * DD + n];
  _Float16 h = (_Float16)v, l = (_Float16)(v - (float)h);
  int kp = (((k >> 3) ^ ((n >> 1) & 3)) << 3) | (k & 7);
  bhi[(size_t)n * DD + kp] = h;
  blo[(size_t)n * DD + kp] = l;
}

// ---------------- fold attention vectors into W matrices ----------------
__global__ void prep_att(const float* __restrict__ Ws, const float* __restrict__ Wd,
                         const float* __restrict__ We, const float* __restrict__ as_,
                         const float* __restrict__ ad_, const float* __restrict__ ae_,
                         float* __restrict__ wmat, float* __restrict__ wea)
{
  int l = blockIdx.x;
  int t = threadIdx.x;
  for (int idx = t; idx < DD * 8; idx += 256) {
    int k = idx >> 3, hd = idx & 7;
    const float* W; const float* att; int hh;
    if (hd < 4) { W = Ws; att = as_; hh = hd; }
    else        { W = Wd; att = ad_; hh = hd - 4; }
    const float* wrow = W + (size_t)l * DD * DD + (size_t)k * DD + hh * CC;
    const float* arow = att + l * DD + hh * CC;
    float s = 0.f;
#pragma unroll 4
    for (int c = 0; c < CC; c++) s = fmaf(wrow[c], arow[c], s);
    wmat[(size_t)l * DD * 8 + idx] = s;
  }
  if (t < 8) {
    int d = t >> 2, hh = t & 3;
    const float* wrow = We + (size_t)l * 2 * DD + (size_t)d * DD + hh * CC;
    const float* arow = ae_ + l * DD + hh * CC;
    float s = 0.f;
#pragma unroll 4
    for (int c = 0; c < CC; c++) s = fmaf(wrow[c], arow[c], s);
    wea[l * 8 + d * 4 + hh] = s;
  }
}

// ---------------- graph boundaries ----------------
__global__ void graph_bounds(const int* __restrict__ batch, int* __restrict__ goff,
                             int N, int G)
{
  int g = threadIdx.x;
  if (g > G) return;
  int lo = 0, hi = N;
  while (lo < hi) { int mid = (lo + hi) >> 1; if (batch[mid] < g) lo = mid + 1; else hi = mid; }
  goff[g] = lo;
}

// ---------------- CSR build by destination ----------------
__global__ void hist_col(const int* __restrict__ ei, int* __restrict__ deg, int E)
{
  int e = blockIdx.x * 256 + threadIdx.x;
  if (e < E) atomicAdd(&deg[ei[E + e]], 1);
}

__global__ void scan1(const int* __restrict__ deg, int* __restrict__ incl,
                      int* __restrict__ bsum, int N)
{
  __shared__ int sm[256];
  int b = blockIdx.x, t = threadIdx.x;
  int i = b * 256 + t;
  int v = (i < N) ? deg[i] : 0;
  sm[t] = v;
  __syncthreads();
  for (int off = 1; off < 256; off <<= 1) {
    int add = (t >= off) ? sm[t - off] : 0;
    __syncthreads();
    sm[t] += add;
    __syncthreads();
  }
  if (i < N) incl[i] = sm[t];
  if (t == 255) bsum[b] = sm[255];
}

__global__ void scan2(int* __restrict__ bsum, int nb)
{
  if (threadIdx.x == 0 && blockIdx.x == 0) {
    int run = 0;
    for (int i = 0; i < nb; i++) { int v = bsum[i]; bsum[i] = run; run += v; }
  }
}

__global__ void scan3(const int* __restrict__ deg, const int* __restrict__ incl,
                      const int* __restrict__ bsum, int* __restrict__ rowptr,
                      int* __restrict__ cur, int N, int E)
{
  int i = blockIdx.x * 256 + threadIdx.x;
  if (i < N) {
    int ex = incl[i] - deg[i] + bsum[blockIdx.x];
    rowptr[i] = ex;
    cur[i] = ex;
  }
  if (i == 0) rowptr[N] = E;
}

__global__ void scatter_edges(const int* __restrict__ ei, const float* __restrict__ eattr,
                              int* __restrict__ cur, int* __restrict__ srow,
                              float2* __restrict__ sea, int E)
{
  int e = blockIdx.x * 256 + threadIdx.x;
  if (e < E) {
    int c = ei[E + e];
    int p = atomicAdd(&cur[c], 1);
    srow[p] = ei[e];
    sea[p] = ((const float2*)eattr)[e];
  }
}

// ---------------- per-node src/dst attention projections (layer 0 only) ----------------
__global__ __launch_bounds__(256) void att_proj(
    const float* __restrict__ h, const float* __restrict__ wmatL,
    float* __restrict__ asrc, float* __restrict__ adst, int N)
{
  __shared__ float Hs[32][260];
  __shared__ float Wm[DD * 8];
  int t = threadIdx.x;
  for (int i = t; i < DD * 8; i += 256) Wm[i] = wmatL[i];
  int n0 = blockIdx.x * 32;
  for (int i = t; i < 32 * 64; i += 256) {
    int n = i >> 6, c4 = i & 63;
    float4 v = {0.f, 0.f, 0.f, 0.f};
    if (n0 + n < N) v = *(const float4*)(h + (size_t)(n0 + n) * DD + c4 * 4);
    Hs[n][c4 * 4 + 0] = v.x; Hs[n][c4 * 4 + 1] = v.y;
    Hs[n][c4 * 4 + 2] = v.z; Hs[n][c4 * 4 + 3] = v.w;
  }
  __syncthreads();
  int n = t >> 3, hd = t & 7;
  float s0 = 0, s1 = 0, s2 = 0, s3 = 0;
  for (int k = 0; k < DD; k += 4) {
    s0 = fmaf(Hs[n][k + 0], Wm[(k + 0) * 8 + hd], s0);
    s1 = fmaf(Hs[n][k + 1], Wm[(k + 1) * 8 + hd], s1);
    s2 = fmaf(Hs[n][k + 2], Wm[(k + 2) * 8 + hd], s2);
    s3 = fmaf(Hs[n][k + 3], Wm[(k + 3) * 8 + hd], s3);
  }
  float s = (s0 + s1) + (s2 + s3);
  int gn = n0 + n;
  if (gn < N) {
    if (hd < 4) asrc[gn * 4 + hd] = s;
    else        adst[gn * 4 + (hd - 4)] = s;
  }
}

// ---------------- fused per-destination kernel ----------------
// one wave per dst node: softmax + weighted message sum + bias + LN + PReLU +
// residual + (fused) next-layer f16 split + (fused) next-layer att projections.
// NOTE: asrcN/adstN must be DIFFERENT buffers from asrc/adst (ping-pong):
// concurrent waves still read the current layer's logits for source nodes.
__global__ __launch_bounds__(256) void dst_fused(
    const float* __restrict__ xs, const float* __restrict__ asrc,
    const float* __restrict__ adst, const int* __restrict__ rowptr,
    const int* __restrict__ srow, const float2* __restrict__ sea,
    const float* __restrict__ weaL, const float* __restrict__ biasL,
    const float* __restrict__ gL, const float* __restrict__ bL,
    const float* __restrict__ pL, float* __restrict__ h,
    _Float16* __restrict__ hhi, _Float16* __restrict__ hlo,
    const float* __restrict__ wnext, float* __restrict__ asrcN,
    float* __restrict__ adstN, int N)
{
  int wid = blockIdx.x * 4 + (threadIdx.x >> 6);
  int lane = threadIdx.x & 63;
  if (wid >= N) return;
  const int head = lane >> 4;
  const int start = rowptr[wid];
  const int end = rowptr[wid + 1];
  const float ad = adst[wid * 4 + head];
  const float w0 = weaL[head];
  const float w1 = weaL[4 + head];
  float ax = 0.f, ay = 0.f, az = 0.f, aw = 0.f;
  float z = 0.f;
  int p = start;
  for (; p + 4 <= end; p += 4) {           // 4x unroll: deep gather pipelining
    int r0 = srow[p], r1 = srow[p + 1], r2 = srow[p + 2], r3 = srow[p + 3];
    float2 e0 = sea[p], e1 = sea[p + 1], e2 = sea[p + 2], e3 = sea[p + 3];
    float s0 = asrc[r0 * 4 + head], s1 = asrc[r1 * 4 + head];
    float s2 = asrc[r2 * 4 + head], s3 = asrc[r3 * 4 + head];
    float4 x0 = *(const float4*)(xs + (size_t)r0 * DD + lane * 4);
    float4 x1 = *(const float4*)(xs + (size_t)r1 * DD + lane * 4);
    float4 x2 = *(const float4*)(xs + (size_t)r2 * DD + lane * 4);
    float4 x3 = *(const float4*)(xs + (size_t)r3 * DD + lane * 4);
    float a0 = s0 + ad + e0.x * w0 + e0.y * w1; a0 = a0 > 0.f ? a0 : 0.2f * a0;
    float a1 = s1 + ad + e1.x * w0 + e1.y * w1; a1 = a1 > 0.f ? a1 : 0.2f * a1;
    float a2 = s2 + ad + e2.x * w0 + e2.y * w1; a2 = a2 > 0.f ? a2 : 0.2f * a2;
    float a3 = s3 + ad + e3.x * w0 + e3.y * w1; a3 = a3 > 0.f ? a3 : 0.2f * a3;
    float t0 = __expf(a0), t1 = __expf(a1), t2 = __expf(a2), t3 = __expf(a3);
    z += (t0 + t1) + (t2 + t3);
    ax = fmaf(t0, x0.x, ax); ay = fmaf(t0, x0.y, ay);
    az = fmaf(t0, x0.z, az); aw = fmaf(t0, x0.w, aw);
    ax = fmaf(t1, x1.x, ax); ay = fmaf(t1, x1.y, ay);
    az = fmaf(t1, x1.z, az); aw = fmaf(t1, x1.w, aw);
    ax = fmaf(t2, x2.x, ax); ay = fmaf(t2, x2.y, ay);
    az = fmaf(t2, x2.z, az); aw = fmaf(t2, x2.w, aw);
    ax = fmaf(t3, x3.x, ax); ay = fmaf(t3, x3.y, ay);
    az = fmaf(t3, x3.z, az); aw = fmaf(t3, x3.w, aw);
  }
  for (; p + 2 <= end; p += 2) {
    int r0 = srow[p], r1 = srow[p + 1];
    float2 e0 = sea[p], e1 = sea[p + 1];
    float s0 = asrc[r0 * 4 + head], s1 = asrc[r1 * 4 + head];
    float4 x0 = *(const float4*)(xs + (size_t)r0 * DD + lane * 4);
    float4 x1 = *(const float4*)(xs + (size_t)r1 * DD + lane * 4);
    float a0 = s0 + ad + e0.x * w0 + e0.y * w1; a0 = a0 > 0.f ? a0 : 0.2f * a0;
    float a1 = s1 + ad + e1.x * w0 + e1.y * w1; a1 = a1 > 0.f ? a1 : 0.2f * a1;
    float t0 = __expf(a0), t1 = __expf(a1);
    z += t0 + t1;
    ax = fmaf(t0, x0.x, ax); ay = fmaf(t0, x0.y, ay);
    az = fmaf(t0, x0.z, az); aw = fmaf(t0, x0.w, aw);
    ax = fmaf(t1, x1.x, ax); ay = fmaf(t1, x1.y, ay);
    az = fmaf(t1, x1.z, az); aw = fmaf(t1, x1.w, aw);
  }
  if (p < end) {
    int r = srow[p];
    float2 ea = sea[p];
    float a = asrc[r * 4 + head] + ad + ea.x * w0 + ea.y * w1;
    a = a > 0.f ? a : 0.2f * a;
    float wt = __expf(a);
    z += wt;
    float4 xv = *(const float4*)(xs + (size_t)r * DD + lane * 4);
    ax = fmaf(wt, xv.x, ax); ay = fmaf(wt, xv.y, ay);
    az = fmaf(wt, xv.z, az); aw = fmaf(wt, xv.w, aw);
  }
  float inv = 1.f / (z + 1e-16f);
  float4 bi = *(const float4*)(biasL + lane * 4);
  float o0 = ax * inv + bi.x;
  float o1 = ay * inv + bi.y;
  float o2 = az * inv + bi.z;
  float o3 = aw * inv + bi.w;
  float s = (o0 + o1) + (o2 + o3);
  float q = (o0 * o0 + o1 * o1) + (o2 * o2 + o3 * o3);
#pragma unroll
  for (int off = 32; off; off >>= 1) {
    s += __shfl_xor(s, off, 64);
    q += __shfl_xor(q, off, 64);
  }
  float mu = s * (1.f / 256.f);
  float var = q * (1.f / 256.f) - mu * mu;
  float rs = rsqrtf(var + 1e-5f);
  float4 gg = *(const float4*)(gL + lane * 4);
  float4 bb = *(const float4*)(bL + lane * 4);
  float4 pp = *(const float4*)(pL + lane * 4);
  o0 = (o0 - mu) * rs * gg.x + bb.x;  o0 = o0 > 0.f ? o0 : pp.x * o0;
  o1 = (o1 - mu) * rs * gg.y + bb.y;  o1 = o1 > 0.f ? o1 : pp.y * o1;
  o2 = (o2 - mu) * rs * gg.z + bb.z;  o2 = o2 > 0.f ? o2 : pp.z * o2;
  o3 = (o3 - mu) * rs * gg.w + bb.w;  o3 = o3 > 0.f ? o3 : pp.w * o3;
  float4 hv = *(const float4*)(h + (size_t)wid * DD + lane * 4);
  float4 ov;
  ov.x = o0 + hv.x; ov.y = o1 + hv.y; ov.z = o2 + hv.z; ov.w = o3 + hv.w;
  *(float4*)(h + (size_t)wid * DD + lane * 4) = ov;
  if (hhi) {                                  // fused split for next layer's GEMM
    int gp = (lane >> 1) ^ ((wid >> 1) & 3);
    int off2 = wid * DD + gp * 8 + (lane & 1) * 4;
    half4_t h4, l4;
    h4[0] = (_Float16)ov.x; l4[0] = (_Float16)(ov.x - (float)h4[0]);
    h4[1] = (_Float16)ov.y; l4[1] = (_Float16)(ov.y - (float)h4[1]);
    h4[2] = (_Float16)ov.z; l4[2] = (_Float16)(ov.z - (float)h4[2]);
    h4[3] = (_Float16)ov.w; l4[3] = (_Float16)(ov.w - (float)h4[3]);
    *(half4_t*)(hhi + off2) = h4;
    *(half4_t*)(hlo + off2) = l4;
  }
  if (wnext) {                                // fused att projections, next layer
    float pr[8];
#pragma unroll
    for (int hd = 0; hd < 8; hd++) {
      const float* wr = wnext + (size_t)(lane * 4) * 8 + hd;
      pr[hd] = ov.x * wr[0] + ov.y * wr[8] + ov.z * wr[16] + ov.w * wr[24];
    }
#pragma unroll
    for (int off = 32; off; off >>= 1) {
#pragma unroll
      for (int hd = 0; hd < 8; hd++) pr[hd] += __shfl_xor(pr[hd], off, 64);
    }
    if (lane == 0) {
      asrcN[wid * 4 + 0] = pr[0]; asrcN[wid * 4 + 1] = pr[1];
      asrcN[wid * 4 + 2] = pr[2]; asrcN[wid * 4 + 3] = pr[3];
      adstN[wid * 4 + 0] = pr[4]; adstN[wid * 4 + 1] = pr[5];
      adstN[wid * 4 + 2] = pr[6]; adstN[wid * 4 + 3] = pr[7];
    }
  }
}

// ---------------- per-graph mean ----------------
__global__ void mean_accum(const float* __restrict__ x, const int* __restrict__ goff,
                           float* __restrict__ msum)
{
  int g = blockIdx.x, sp = blockIdx.y, t = threadIdx.x;
  int lo = goff[g], hi = goff[g + 1];
  int cnt = hi - lo;
  if (cnt <= 0) return;
  int per = (cnt + gridDim.y - 1) / gridDim.y;
  int st = lo + sp * per;
  int en = min(hi, st + per);
  if (st >= en) return;
  float acc = 0.f;
  for (int n = st; n < en; ++n) acc += x[(size_t)n * DD + t];
  atomicAdd(&msum[g * DD + t], acc);
}

__global__ void mean_fin(const float* __restrict__ msum, const int* __restrict__ goff,
                         float* __restrict__ dst)
{
  int g = blockIdx.x, t = threadIdx.x;
  int cnt = goff[g + 1] - goff[g];
  dst[g * DD + t] = msum[g * DD + t] / fmaxf((float)cnt, 1.f);
}

// ---------------- head MLP ----------------
__global__ __launch_bounds__(256) void head_mlp(
    const float* __restrict__ hmean, const float* __restrict__ W1,
    const float* __restrict__ b1, const float* __restrict__ W2,
    const float* __restrict__ b2, const float* __restrict__ Wr,
    const float* __restrict__ br, float* __restrict__ out)
{
  __shared__ float xc[4 * DD];
  __shared__ float p1[DD];
  __shared__ float red[256];
  int g = blockIdx.x, t = threadIdx.x;
  float m0 = hmean[0 * GG * DD + g * DD + t];
  float m1 = hmean[1 * GG * DD + g * DD + t];
  float m2 = hmean[2 * GG * DD + g * DD + t];
  float m3 = hmean[3 * GG * DD + g * DD + t];
  xc[t] = m0;
  xc[DD + t] = m1 - m0;
  xc[2 * DD + t] = m2 - m1;
  xc[3 * DD + t] = m3 - m2;
  __syncthreads();
  float acc = b1[t];
  for (int k = 0; k < 4 * DD; k++) acc = fmaf(xc[k], W1[(size_t)k * DD + t], acc);
  p1[t] = fmaxf(acc, 0.f);
  __syncthreads();
  float acc2 = b2[t];
  for (int k = 0; k < DD; k++) acc2 = fmaf(p1[k], W2[(size_t)k * DD + t], acc2);
  float v = fmaxf(acc2, 0.f) * Wr[t];
  red[t] = v;
  __syncthreads();
  for (int sdown = 128; sdown; sdown >>= 1) {
    if (t < sdown) red[t] += red[t + sdown];
    __syncthreads();
  }
  if (t == 0) out[g] = red[0] + br[0];
}

// ---------------- launch ----------------
extern "C" void kernel_launch(void* const* d_in, const int* in_sizes, int n_in,
                              void* d_out, int out_size, void* d_ws, size_t ws_size,
                              hipStream_t stream)
{
  const float* x        = (const float*)d_in[0];
  const float* eattr    = (const float*)d_in[1];
  const int*   eidx     = (const int*)d_in[2];
  const int*   batch    = (const int*)d_in[3];
  const float* W_pre    = (const float*)d_in[4];
  const float* b_pre    = (const float*)d_in[5];
  const float* W_src    = (const float*)d_in[6];
  const float* W_dst    = (const float*)d_in[7];
  const float* W_edge   = (const float*)d_in[8];
  const float* att_src  = (const float*)d_in[9];
  const float* att_dst  = (const float*)d_in[10];
  const float* att_edge = (const float*)d_in[11];
  const float* bias_conv= (const float*)d_in[12];
  const float* ln_g     = (const float*)d_in[13];
  const float* ln_b     = (const float*)d_in[14];
  const float* prelu    = (const float*)d_in[15];
  const float* W1       = (const float*)d_in[16];
  const float* b1       = (const float*)d_in[17];
  const float* W2       = (const float*)d_in[18];
  const float* b2       = (const float*)d_in[19];
  const float* Wr       = (const float*)d_in[20];
  const float* br       = (const float*)d_in[21];
  float* out = (float*)d_out;

  char* w = (char*)d_ws;
  size_t off = 0;
  auto alloc = [&](size_t bytes) -> char* {
    char* p = w + off;
    off += (bytes + 255) & ~(size_t)255;
    return p;
  };
  float*     h     = (float*)alloc((size_t)NN * DD * 4);
  char*      xsreg = alloc((size_t)NPAD * DD * 4);     // xs f32  |  x_hi + x_lo alias
  float*     xs    = (float*)xsreg;
  _Float16*  x_hi  = (_Float16*)xsreg;
  _Float16*  x_lo  = (_Float16*)(xsreg + (size_t)NPAD * DD * 2);
  _Float16*  h_hi  = (_Float16*)alloc((size_t)NPAD * DD * 2);
  _Float16*  h_lo  = (_Float16*)alloc((size_t)NPAD * DD * 2);
  _Float16*  bt_hi = (_Float16*)alloc((size_t)4 * DD * DD * 2);  // W_pre, W_src[0..2]
  _Float16*  bt_lo = (_Float16*)alloc((size_t)4 * DD * DD * 2);
  float*  asrcA = (float*)alloc((size_t)NN * HH * 4);  // ping-pong logit buffers
  float*  adstA = (float*)alloc((size_t)NN * HH * 4);
  float*  asrcB = (float*)alloc((size_t)NN * HH * 4);
  float*  adstB = (float*)alloc((size_t)NN * HH * 4);
  float*  wmat  = (float*)alloc((size_t)LL * DD * 8 * 4);
  float*  wea   = (float*)alloc((size_t)LL * 8 * 4);
  float*  hmean = (float*)alloc((size_t)(LL + 1) * GG * DD * 4);
  float*  msum  = (float*)alloc((size_t)GG * DD * 4);
  float2* sea   = (float2*)alloc((size_t)EE * 8);
  int*    goff  = (int*)alloc((GG + 1) * 4);
  int*    deg   = (int*)alloc((size_t)NN * 4);
  int*    rowptr= (int*)alloc((size_t)(NN + 1) * 4);
  int*    cur   = (int*)alloc((size_t)NN * 4);
  int*    incl  = (int*)alloc((size_t)NN * 4);
  int*    bsum  = (int*)alloc(256 * 4);
  int*    srow  = (int*)alloc((size_t)EE * 4);
  if (off > ws_size) return;

  // precomputes + CSR build
  prep_att<<<dim3(LL), dim3(256), 0, stream>>>(W_src, W_dst, W_edge, att_src,
                                               att_dst, att_edge, wmat, wea);
  prep_w<<<dim3(DD), dim3(DD), 0, stream>>>(W_pre, bt_hi, bt_lo);
  for (int l = 0; l < LL; l++)
    prep_w<<<dim3(DD), dim3(DD), 0, stream>>>(W_src + (size_t)l * DD * DD,
                                              bt_hi + (size_t)(l + 1) * DD * DD,
                                              bt_lo + (size_t)(l + 1) * DD * DD);
  graph_bounds<<<dim3(1), dim3(32), 0, stream>>>(batch, goff, NN, GG);
  hipMemsetAsync(deg, 0, (size_t)NN * 4, stream);
  hist_col<<<dim3((EE + 255) / 256), dim3(256), 0, stream>>>(eidx, deg, EE);
  int nb = (NN + 255) / 256;
  scan1<<<dim3(nb), dim3(256), 0, stream>>>(deg, incl, bsum, NN);
  scan2<<<dim3(1), dim3(1), 0, stream>>>(bsum, nb);
  scan3<<<dim3(nb), dim3(256), 0, stream>>>(deg, incl, bsum, rowptr, cur, NN, EE);
  scatter_edges<<<dim3((EE + 255) / 256), dim3(256), 0, stream>>>(eidx, eattr, cur,
                                                                  srow, sea, EE);

  // h = x @ W_pre + b_pre  (via f16 split MFMA)
  split_f16<<<dim3((NN * 64 + 255) / 256), dim3(256), 0, stream>>>(x, x_hi, x_lo, NN);
  dim3 gg((NN + 127) / 128, 2);
  gemm_mfma<<<gg, dim3(256), 0, stream>>>(x_hi, x_lo, bt_hi, bt_lo, b_pre, h, NN);
  split_f16<<<dim3((NN * 64 + 255) / 256), dim3(256), 0, stream>>>(h, h_hi, h_lo, NN);
  att_proj<<<dim3((NN + 31) / 32), dim3(256), 0, stream>>>(h, wmat, asrcA, adstA, NN);
  hipMemsetAsync(msum, 0, (size_t)GG * DD * 4, stream);
  mean_accum<<<dim3(GG, 16), dim3(DD), 0, stream>>>(h, goff, msum);
  mean_fin<<<dim3(GG), dim3(DD), 0, stream>>>(msum, goff, hmean);

  for (int l = 0; l < LL; l++) {
    gemm_mfma<<<gg, dim3(256), 0, stream>>>(h_hi, h_lo,
                                            bt_hi + (size_t)(l + 1) * DD * DD,
                                            bt_lo + (size_t)(l + 1) * DD * DD,
                                            (const float*)nullptr, xs, NN);
    bool ws = (l < LL - 1);
    const float* aS = (l & 1) ? asrcB : asrcA;   // read current layer's logits
    const float* aD = (l & 1) ? adstB : adstA;
    float* aSN = (l & 1) ? asrcA : asrcB;        // write NEXT layer's logits
    float* aDN = (l & 1) ? adstA : adstB;
    dst_fused<<<dim3((NN + 3) / 4), dim3(256), 0, stream>>>(
        xs, aS, aD, rowptr, srow, sea, wea + l * 8, bias_conv + l * DD,
        ln_g + l * DD, ln_b + l * DD, prelu + l * DD, h,
        ws ? h_hi : (_Float16*)nullptr, ws ? h_lo : (_Float16*)nullptr,
        ws ? (wmat + (size_t)(l + 1) * DD * 8) : (const float*)nullptr,
        aSN, aDN, NN);
    hipMemsetAsync(msum, 0, (size_t)GG * DD * 4, stream);
    mean_accum<<<dim3(GG, 16), dim3(DD), 0, stream>>>(h, goff, msum);
    mean_fin<<<dim3(GG), dim3(DD), 0, stream>>>(msum, goff,
                                                hmean + (size_t)(l + 1) * GG * DD);
  }

  head_mlp<<<dim3(GG), dim3(256), 0, stream>>>(hmean, W1, b1, W2, b2, Wr, br, out);
}

// Round 9
// 845.663 us; speedup vs baseline: 1.3650x; 1.1065x over previous
//
#include <hip/hip_runtime.h>
#include <math.h>

#define NN 50000
#define NPAD 50048
#define EE 400000
#define DD 256
#define HH 4
#define CC 64
#define LL 3
#define GG 25

typedef _Float16 half4_t __attribute__((ext_vector_type(4)));
typedef _Float16 half8_t __attribute__((ext_vector_type(8)));
typedef float f32x4_t __attribute__((ext_vector_type(4)));

// ================= split-f16 MFMA GEMM, 2-phase double-buffered =================
// A,W as swizzled f16 hi/lo; swizzle col k' = ((k>>3) ^ ((r>>1)&3))<<3 | (k&7).
// Output: either f32 C (+bias) or f16 C16 (no bias).
__global__ __launch_bounds__(256) void gemm_mfma(
    const _Float16* __restrict__ Ahi, const _Float16* __restrict__ Alo,
    const _Float16* __restrict__ Bhi, const _Float16* __restrict__ Blo,
    const float* __restrict__ bias, float* __restrict__ C,
    _Float16* __restrict__ C16, int N)
{
  __shared__ _Float16 lds[2][4][128][32];   // 2 bufs x {Ahi,Alo,Bhi,Blo} = 64 KB
  const int t = threadIdx.x;
  const int wave = t >> 6, lane = t & 63;
  const int m0 = blockIdx.x * 128, bn0 = blockIdx.y * 128;
  const int wm = wave >> 1, wn = wave & 1;

  f32x4_t acc[4][4];
#pragma unroll
  for (int i = 0; i < 4; i++)
#pragma unroll
    for (int j = 0; j < 4; j++) acc[i][j] = (f32x4_t){0.f, 0.f, 0.f, 0.f};

  const int l15 = lane & 15, kg = lane >> 4;
  int aoff[4], boff[4];
#pragma unroll
  for (int tr = 0; tr < 4; tr++) {
    int r = wm * 64 + tr * 16 + l15;
    aoff[tr] = r * 64 + ((kg ^ ((r >> 1) & 3)) * 16);
    int n = wn * 64 + tr * 16 + l15;
    boff[tr] = n * 64 + ((kg ^ ((n >> 1) & 3)) * 16);
  }

  const _Float16* gsrc[4];
  gsrc[0] = Ahi + (size_t)m0 * 256;
  gsrc[1] = Alo + (size_t)m0 * 256;
  gsrc[2] = Bhi + (size_t)bn0 * 256;
  gsrc[3] = Blo + (size_t)bn0 * 256;

  char* lbase = (char*)&lds[0][0][0][0];
  const int rowbase0 = (wave << 5);

  auto stage = [&](int buf, int k0) {
#pragma unroll
    for (int b = 0; b < 4; b++) {
#pragma unroll
      for (int c = 0; c < 2; c++) {
        int rowbase = rowbase0 + (c << 4);
        const _Float16* g = gsrc[b] + (size_t)(rowbase + (lane >> 2)) * 256
                            + k0 + (lane & 3) * 8;
        char* l = lbase + (size_t)(buf * 4 + b) * 8192 + rowbase * 64;
        __builtin_amdgcn_global_load_lds(
            (const __attribute__((address_space(1))) void*)g,
            (__attribute__((address_space(3))) void*)l, 16, 0, 0);
      }
    }
  };

  stage(0, 0);
  __syncthreads();                         // prologue drain: buf0 ready
  int cur = 0;
  for (int k0 = 0; k0 < DD; k0 += 32) {
    if (k0 + 32 < DD) stage(cur ^ 1, k0 + 32);   // prefetch next tile (in flight)

    const char* lb = lbase + (size_t)cur * 4 * 8192;
    half8_t ah[4], al[4], bh[4], bl[4];
#pragma unroll
    for (int i = 0; i < 4; i++) {
      ah[i] = *(const half8_t*)(lb + 0 * 8192 + aoff[i]);
      al[i] = *(const half8_t*)(lb + 1 * 8192 + aoff[i]);
      bh[i] = *(const half8_t*)(lb + 2 * 8192 + boff[i]);
      bl[i] = *(const half8_t*)(lb + 3 * 8192 + boff[i]);
    }
#pragma unroll
    for (int i = 0; i < 4; i++)
#pragma unroll
      for (int j = 0; j < 4; j++) {
        acc[i][j] = __builtin_amdgcn_mfma_f32_16x16x32_f16(ah[i], bh[j], acc[i][j], 0, 0, 0);
        acc[i][j] = __builtin_amdgcn_mfma_f32_16x16x32_f16(ah[i], bl[j], acc[i][j], 0, 0, 0);
        acc[i][j] = __builtin_amdgcn_mfma_f32_16x16x32_f16(al[i], bh[j], acc[i][j], 0, 0, 0);
      }
    __syncthreads();                       // drains next-tile vmcnt + barrier
    cur ^= 1;
  }

  if (C16) {                               // f16 output (xs messages), no bias
#pragma unroll
    for (int i = 0; i < 4; i++) {
      int rb = m0 + wm * 64 + i * 16 + (lane >> 4) * 4;
#pragma unroll
      for (int j = 0; j < 4; j++) {
        int col = bn0 + wn * 64 + j * 16 + l15;
#pragma unroll
        for (int q = 0; q < 4; q++) {
          int r = rb + q;
          if (r < N) C16[(size_t)r * DD + col] = (_Float16)acc[i][j][q];
        }
      }
    }
  } else {                                 // f32 output + bias
#pragma unroll
    for (int i = 0; i < 4; i++) {
      int rb = m0 + wm * 64 + i * 16 + (lane >> 4) * 4;
#pragma unroll
      for (int j = 0; j < 4; j++) {
        int col = bn0 + wn * 64 + j * 16 + l15;
        float bv = bias ? bias[col] : 0.f;
#pragma unroll
        for (int q = 0; q < 4; q++) {
          int r = rb + q;
          if (r < N) C[(size_t)r * DD + col] = acc[i][j][q] + bv;
        }
      }
    }
  }
}

// ---------------- f32 -> swizzled f16 hi/lo split ----------------
__global__ __launch_bounds__(256) void split_f16(
    const float* __restrict__ src, _Float16* __restrict__ hi,
    _Float16* __restrict__ lo, int N)
{
  int f = blockIdx.x * 256 + threadIdx.x;    // float4 index
  if (f >= N * 64) return;
  int m = f >> 6, q = f & 63;
  float4 v = *(const float4*)(src + (size_t)f * 4);
  int gp = (q >> 1) ^ ((m >> 1) & 3);
  int off = m * 256 + gp * 8 + (q & 1) * 4;
  half4_t h4, l4;
  h4[0] = (_Float16)v.x; l4[0] = (_Float16)(v.x - (float)h4[0]);
  h4[1] = (_Float16)v.y; l4[1] = (_Float16)(v.y - (float)h4[1]);
  h4[2] = (_Float16)v.z; l4[2] = (_Float16)(v.z - (float)h4[2]);
  h4[3] = (_Float16)v.w; l4[3] = (_Float16)(v.w - (float)h4[3]);
  *(half4_t*)(hi + off) = h4;
  *(half4_t*)(lo + off) = l4;
}

// ---------------- W[256][256] -> transposed swizzled f16 hi/lo ----------------
__global__ void prep_w(const float* __restrict__ W, _Float16* __restrict__ bhi,
                       _Float16* __restrict__ blo)
{
  int n = blockIdx.x, k = threadIdx.x;
  float v = W[(size_t)k * DD + n];
  _Float16 h = (_Float16)v, l = (_Float16)(v - (float)h);
  int kp = (((k >> 3) ^ ((n >> 1) & 3)) << 3) | (k & 7);
  bhi[(size_t)n * DD + kp] = h;
  blo[(size_t)n * DD + kp] = l;
}

// ---------------- fold attention vectors into W matrices ----------------
__global__ void prep_att(const float* __restrict__ Ws, const float* __restrict__ Wd,
                         const float* __restrict__ We, const float* __restrict__ as_,
                         const float* __restrict__ ad_, const float* __restrict__ ae_,
                         float* __restrict__ wmat, float* __restrict__ wea)
{
  int l = blockIdx.x;
  int t = threadIdx.x;
  for (int idx = t; idx < DD * 8; idx += 256) {
    int k = idx >> 3, hd = idx & 7;
    const float* W; const float* att; int hh;
    if (hd < 4) { W = Ws; att = as_; hh = hd; }
    else        { W = Wd; att = ad_; hh = hd - 4; }
    const float* wrow = W + (size_t)l * DD * DD + (size_t)k * DD + hh * CC;
    const float* arow = att + l * DD + hh * CC;
    float s = 0.f;
#pragma unroll 4
    for (int c = 0; c < CC; c++) s = fmaf(wrow[c], arow[c], s);
    wmat[(size_t)l * DD * 8 + idx] = s;
  }
  if (t < 8) {
    int d = t >> 2, hh = t & 3;
    const float* wrow = We + (size_t)l * 2 * DD + (size_t)d * DD + hh * CC;
    const float* arow = ae_ + l * DD + hh * CC;
    float s = 0.f;
#pragma unroll 4
    for (int c = 0; c < CC; c++) s = fmaf(wrow[c], arow[c], s);
    wea[l * 8 + d * 4 + hh] = s;
  }
}

// ---------------- graph boundaries ----------------
__global__ void graph_bounds(const int* __restrict__ batch, int* __restrict__ goff,
                             int N, int G)
{
  int g = threadIdx.x;
  if (g > G) return;
  int lo = 0, hi = N;
  while (lo < hi) { int mid = (lo + hi) >> 1; if (batch[mid] < g) lo = mid + 1; else hi = mid; }
  goff[g] = lo;
}

// ---------------- CSR build by destination ----------------
__global__ void hist_col(const int* __restrict__ ei, int* __restrict__ deg, int E)
{
  int e = blockIdx.x * 256 + threadIdx.x;
  if (e < E) atomicAdd(&deg[ei[E + e]], 1);
}

__global__ void scan1(const int* __restrict__ deg, int* __restrict__ incl,
                      int* __restrict__ bsum, int N)
{
  __shared__ int sm[256];
  int b = blockIdx.x, t = threadIdx.x;
  int i = b * 256 + t;
  int v = (i < N) ? deg[i] : 0;
  sm[t] = v;
  __syncthreads();
  for (int off = 1; off < 256; off <<= 1) {
    int add = (t >= off) ? sm[t - off] : 0;
    __syncthreads();
    sm[t] += add;
    __syncthreads();
  }
  if (i < N) incl[i] = sm[t];
  if (t == 255) bsum[b] = sm[255];
}

// one-block parallel exclusive scan of block sums (nb <= 256)
__global__ void scan2(int* __restrict__ bsum, int nb)
{
  __shared__ int sm[256];
  int t = threadIdx.x;
  int v = (t < nb) ? bsum[t] : 0;
  sm[t] = v;
  __syncthreads();
  for (int off = 1; off < 256; off <<= 1) {
    int add = (t >= off) ? sm[t - off] : 0;
    __syncthreads();
    sm[t] += add;
    __syncthreads();
  }
  if (t < nb) bsum[t] = sm[t] - v;   // exclusive
}

__global__ void scan3(const int* __restrict__ deg, const int* __restrict__ incl,
                      const int* __restrict__ bsum, int* __restrict__ rowptr,
                      int* __restrict__ cur, int N, int E)
{
  int i = blockIdx.x * 256 + threadIdx.x;
  if (i < N) {
    int ex = incl[i] - deg[i] + bsum[blockIdx.x];
    rowptr[i] = ex;
    cur[i] = ex;
  }
  if (i == 0) rowptr[N] = E;
}

__global__ void scatter_edges(const int* __restrict__ ei, const float* __restrict__ eattr,
                              int* __restrict__ cur, int* __restrict__ srow,
                              float2* __restrict__ sea, int E)
{
  int e = blockIdx.x * 256 + threadIdx.x;
  if (e < E) {
    int c = ei[E + e];
    int p = atomicAdd(&cur[c], 1);
    srow[p] = ei[e];
    sea[p] = ((const float2*)eattr)[e];
  }
}

// ---------------- per-node src/dst attention projections ----------------
__global__ __launch_bounds__(256) void att_proj(
    const float* __restrict__ h, const float* __restrict__ wmatL,
    float* __restrict__ asrc, float* __restrict__ adst, int N)
{
  __shared__ float Hs[32][260];
  __shared__ float Wm[DD * 8];
  int t = threadIdx.x;
  for (int i = t; i < DD * 8; i += 256) Wm[i] = wmatL[i];
  int n0 = blockIdx.x * 32;
  for (int i = t; i < 32 * 64; i += 256) {
    int n = i >> 6, c4 = i & 63;
    float4 v = {0.f, 0.f, 0.f, 0.f};
    if (n0 + n < N) v = *(const float4*)(h + (size_t)(n0 + n) * DD + c4 * 4);
    Hs[n][c4 * 4 + 0] = v.x; Hs[n][c4 * 4 + 1] = v.y;
    Hs[n][c4 * 4 + 2] = v.z; Hs[n][c4 * 4 + 3] = v.w;
  }
  __syncthreads();
  int n = t >> 3, hd = t & 7;
  float s0 = 0, s1 = 0, s2 = 0, s3 = 0;
  for (int k = 0; k < DD; k += 4) {
    s0 = fmaf(Hs[n][k + 0], Wm[(k + 0) * 8 + hd], s0);
    s1 = fmaf(Hs[n][k + 1], Wm[(k + 1) * 8 + hd], s1);
    s2 = fmaf(Hs[n][k + 2], Wm[(k + 2) * 8 + hd], s2);
    s3 = fmaf(Hs[n][k + 3], Wm[(k + 3) * 8 + hd], s3);
  }
  float s = (s0 + s1) + (s2 + s3);
  int gn = n0 + n;
  if (gn < N) {
    if (hd < 4) asrc[gn * 4 + hd] = s;
    else        adst[gn * 4 + (hd - 4)] = s;
  }
}

// ---------------- fused per-destination kernel (f16 message gather) ----------------
__global__ __launch_bounds__(256) void dst_fused(
    const _Float16* __restrict__ xs16, const float* __restrict__ asrc,
    const float* __restrict__ adst, const int* __restrict__ rowptr,
    const int* __restrict__ srow, const float2* __restrict__ sea,
    const float* __restrict__ weaL, const float* __restrict__ biasL,
    const float* __restrict__ gL, const float* __restrict__ bL,
    const float* __restrict__ pL, float* __restrict__ h,
    _Float16* __restrict__ hhi, _Float16* __restrict__ hlo, int N)
{
  int wid = blockIdx.x * 4 + (threadIdx.x >> 6);
  int lane = threadIdx.x & 63;
  if (wid >= N) return;
  const int head = lane >> 4;
  const int start = rowptr[wid];
  const int end = rowptr[wid + 1];
  const float ad = adst[wid * 4 + head];
  const float w0 = weaL[head];
  const float w1 = weaL[4 + head];
  float ax = 0.f, ay = 0.f, az = 0.f, aw = 0.f;
  float z = 0.f;
  int p = start;
  for (; p + 2 <= end; p += 2) {           // 2x unroll: overlap gather latency
    int r0 = srow[p], r1 = srow[p + 1];
    float2 e0 = sea[p], e1 = sea[p + 1];
    float s0 = asrc[r0 * 4 + head], s1 = asrc[r1 * 4 + head];
    half4_t x0 = *(const half4_t*)(xs16 + (size_t)r0 * DD + lane * 4);
    half4_t x1 = *(const half4_t*)(xs16 + (size_t)r1 * DD + lane * 4);
    float a0 = s0 + ad + e0.x * w0 + e0.y * w1; a0 = a0 > 0.f ? a0 : 0.2f * a0;
    float a1 = s1 + ad + e1.x * w0 + e1.y * w1; a1 = a1 > 0.f ? a1 : 0.2f * a1;
    float t0 = __expf(a0), t1 = __expf(a1);
    z += t0 + t1;
    ax = fmaf(t0, (float)x0[0], ax); ay = fmaf(t0, (float)x0[1], ay);
    az = fmaf(t0, (float)x0[2], az); aw = fmaf(t0, (float)x0[3], aw);
    ax = fmaf(t1, (float)x1[0], ax); ay = fmaf(t1, (float)x1[1], ay);
    az = fmaf(t1, (float)x1[2], az); aw = fmaf(t1, (float)x1[3], aw);
  }
  if (p < end) {
    int r = srow[p];
    float2 ea = sea[p];
    float a = asrc[r * 4 + head] + ad + ea.x * w0 + ea.y * w1;
    a = a > 0.f ? a : 0.2f * a;
    float wt = __expf(a);
    z += wt;
    half4_t xv = *(const half4_t*)(xs16 + (size_t)r * DD + lane * 4);
    ax = fmaf(wt, (float)xv[0], ax); ay = fmaf(wt, (float)xv[1], ay);
    az = fmaf(wt, (float)xv[2], az); aw = fmaf(wt, (float)xv[3], aw);
  }
  float inv = 1.f / (z + 1e-16f);
  float4 bi = *(const float4*)(biasL + lane * 4);
  float o0 = ax * inv + bi.x;
  float o1 = ay * inv + bi.y;
  float o2 = az * inv + bi.z;
  float o3 = aw * inv + bi.w;
  float s = (o0 + o1) + (o2 + o3);
  float q = (o0 * o0 + o1 * o1) + (o2 * o2 + o3 * o3);
#pragma unroll
  for (int off = 32; off; off >>= 1) {
    s += __shfl_xor(s, off, 64);
    q += __shfl_xor(q, off, 64);
  }
  float mu = s * (1.f / 256.f);
  float var = q * (1.f / 256.f) - mu * mu;
  float rs = rsqrtf(var + 1e-5f);
  float4 gg = *(const float4*)(gL + lane * 4);
  float4 bb = *(const float4*)(bL + lane * 4);
  float4 pp = *(const float4*)(pL + lane * 4);
  o0 = (o0 - mu) * rs * gg.x + bb.x;  o0 = o0 > 0.f ? o0 : pp.x * o0;
  o1 = (o1 - mu) * rs * gg.y + bb.y;  o1 = o1 > 0.f ? o1 : pp.y * o1;
  o2 = (o2 - mu) * rs * gg.z + bb.z;  o2 = o2 > 0.f ? o2 : pp.z * o2;
  o3 = (o3 - mu) * rs * gg.w + bb.w;  o3 = o3 > 0.f ? o3 : pp.w * o3;
  float4 hv = *(const float4*)(h + (size_t)wid * DD + lane * 4);
  float4 ov;
  ov.x = o0 + hv.x; ov.y = o1 + hv.y; ov.z = o2 + hv.z; ov.w = o3 + hv.w;
  *(float4*)(h + (size_t)wid * DD + lane * 4) = ov;
  if (hhi) {                                  // fused split for next layer's GEMM
    int gp = (lane >> 1) ^ ((wid >> 1) & 3);
    int off2 = wid * DD + gp * 8 + (lane & 1) * 4;
    half4_t h4, l4;
    h4[0] = (_Float16)ov.x; l4[0] = (_Float16)(ov.x - (float)h4[0]);
    h4[1] = (_Float16)ov.y; l4[1] = (_Float16)(ov.y - (float)h4[1]);
    h4[2] = (_Float16)ov.z; l4[2] = (_Float16)(ov.z - (float)h4[2]);
    h4[3] = (_Float16)ov.w; l4[3] = (_Float16)(ov.w - (float)h4[3]);
    *(half4_t*)(hhi + off2) = h4;
    *(half4_t*)(hlo + off2) = l4;
  }
}

// ---------------- per-graph mean ----------------
__global__ void mean_accum(const float* __restrict__ x, const int* __restrict__ goff,
                           float* __restrict__ msum)
{
  int g = blockIdx.x, sp = blockIdx.y, t = threadIdx.x;
  int lo = goff[g], hi = goff[g + 1];
  int cnt = hi - lo;
  if (cnt <= 0) return;
  int per = (cnt + gridDim.y - 1) / gridDim.y;
  int st = lo + sp * per;
  int en = min(hi, st + per);
  if (st >= en) return;
  float acc = 0.f;
  for (int n = st; n < en; ++n) acc += x[(size_t)n * DD + t];
  atomicAdd(&msum[g * DD + t], acc);
}

__global__ void mean_fin(const float* __restrict__ msum, const int* __restrict__ goff,
                         float* __restrict__ dst)
{
  int g = blockIdx.x, t = threadIdx.x;
  int cnt = goff[g + 1] - goff[g];
  dst[g * DD + t] = msum[g * DD + t] / fmaxf((float)cnt, 1.f);
}

// ---------------- head MLP ----------------
__global__ __launch_bounds__(256) void head_mlp(
    const float* __restrict__ hmean, const float* __restrict__ W1,
    const float* __restrict__ b1, const float* __restrict__ W2,
    const float* __restrict__ b2, const float* __restrict__ Wr,
    const float* __restrict__ br, float* __restrict__ out)
{
  __shared__ float xc[4 * DD];
  __shared__ float p1[DD];
  __shared__ float red[256];
  int g = blockIdx.x, t = threadIdx.x;
  float m0 = hmean[0 * GG * DD + g * DD + t];
  float m1 = hmean[1 * GG * DD + g * DD + t];
  float m2 = hmean[2 * GG * DD + g * DD + t];
  float m3 = hmean[3 * GG * DD + g * DD + t];
  xc[t] = m0;
  xc[DD + t] = m1 - m0;
  xc[2 * DD + t] = m2 - m1;
  xc[3 * DD + t] = m3 - m2;
  __syncthreads();
  float acc = b1[t];
  for (int k = 0; k < 4 * DD; k++) acc = fmaf(xc[k], W1[(size_t)k * DD + t], acc);
  p1[t] = fmaxf(acc, 0.f);
  __syncthreads();
  float acc2 = b2[t];
  for (int k = 0; k < DD; k++) acc2 = fmaf(p1[k], W2[(size_t)k * DD + t], acc2);
  float v = fmaxf(acc2, 0.f) * Wr[t];
  red[t] = v;
  __syncthreads();
  for (int sdown = 128; sdown; sdown >>= 1) {
    if (t < sdown) red[t] += red[t + sdown];
    __syncthreads();
  }
  if (t == 0) out[g] = red[0] + br[0];
}

// ---------------- launch ----------------
extern "C" void kernel_launch(void* const* d_in, const int* in_sizes, int n_in,
                              void* d_out, int out_size, void* d_ws, size_t ws_size,
                              hipStream_t stream)
{
  const float* x        = (const float*)d_in[0];
  const float* eattr    = (const float*)d_in[1];
  const int*   eidx     = (const int*)d_in[2];
  const int*   batch    = (const int*)d_in[3];
  const float* W_pre    = (const float*)d_in[4];
  const float* b_pre    = (const float*)d_in[5];
  const float* W_src    = (const float*)d_in[6];
  const float* W_dst    = (const float*)d_in[7];
  const float* W_edge   = (const float*)d_in[8];
  const float* att_src  = (const float*)d_in[9];
  const float* att_dst  = (const float*)d_in[10];
  const float* att_edge = (const float*)d_in[11];
  const float* bias_conv= (const float*)d_in[12];
  const float* ln_g     = (const float*)d_in[13];
  const float* ln_b     = (const float*)d_in[14];
  const float* prelu    = (const float*)d_in[15];
  const float* W1       = (const float*)d_in[16];
  const float* b1       = (const float*)d_in[17];
  const float* W2       = (const float*)d_in[18];
  const float* b2       = (const float*)d_in[19];
  const float* Wr       = (const float*)d_in[20];
  const float* br       = (const float*)d_in[21];
  float* out = (float*)d_out;

  char* w = (char*)d_ws;
  size_t off = 0;
  auto alloc = [&](size_t bytes) -> char* {
    char* p = w + off;
    off += (bytes + 255) & ~(size_t)255;
    return p;
  };
  float*     h     = (float*)alloc((size_t)NN * DD * 4);
  char*      xsreg = alloc((size_t)NPAD * DD * 4);     // x_hi+x_lo | later xs16
  _Float16*  x_hi  = (_Float16*)xsreg;
  _Float16*  x_lo  = (_Float16*)(xsreg + (size_t)NPAD * DD * 2);
  _Float16*  xs16  = (_Float16*)xsreg;                  // aliases x_hi (dead by then)
  _Float16*  h_hi  = (_Float16*)alloc((size_t)NPAD * DD * 2);
  _Float16*  h_lo  = (_Float16*)alloc((size_t)NPAD * DD * 2);
  _Float16*  bt_hi = (_Float16*)alloc((size_t)4 * DD * DD * 2);  // W_pre, W_src[0..2]
  _Float16*  bt_lo = (_Float16*)alloc((size_t)4 * DD * DD * 2);
  float*  asrc  = (float*)alloc((size_t)NN * HH * 4);
  float*  adst  = (float*)alloc((size_t)NN * HH * 4);
  float*  wmat  = (float*)alloc((size_t)LL * DD * 8 * 4);
  float*  wea   = (float*)alloc((size_t)LL * 8 * 4);
  float*  hmean = (float*)alloc((size_t)(LL + 1) * GG * DD * 4);
  float*  msum  = (float*)alloc((size_t)GG * DD * 4);
  float2* sea   = (float2*)alloc((size_t)EE * 8);
  int*    goff  = (int*)alloc((GG + 1) * 4);
  int*    deg   = (int*)alloc((size_t)NN * 4);
  int*    rowptr= (int*)alloc((size_t)(NN + 1) * 4);
  int*    cur   = (int*)alloc((size_t)NN * 4);
  int*    incl  = (int*)alloc((size_t)NN * 4);
  int*    bsum  = (int*)alloc(256 * 4);
  int*    srow  = (int*)alloc((size_t)EE * 4);
  if (off > ws_size) return;

  // precomputes + CSR build
  prep_att<<<dim3(LL), dim3(256), 0, stream>>>(W_src, W_dst, W_edge, att_src,
                                               att_dst, att_edge, wmat, wea);
  prep_w<<<dim3(DD), dim3(DD), 0, stream>>>(W_pre, bt_hi, bt_lo);
  for (int l = 0; l < LL; l++)
    prep_w<<<dim3(DD), dim3(DD), 0, stream>>>(W_src + (size_t)l * DD * DD,
                                              bt_hi + (size_t)(l + 1) * DD * DD,
                                              bt_lo + (size_t)(l + 1) * DD * DD);
  graph_bounds<<<dim3(1), dim3(32), 0, stream>>>(batch, goff, NN, GG);
  hipMemsetAsync(deg, 0, (size_t)NN * 4, stream);
  hist_col<<<dim3((EE + 255) / 256), dim3(256), 0, stream>>>(eidx, deg, EE);
  int nb = (NN + 255) / 256;
  scan1<<<dim3(nb), dim3(256), 0, stream>>>(deg, incl, bsum, NN);
  scan2<<<dim3(1), dim3(256), 0, stream>>>(bsum, nb);
  scan3<<<dim3(nb), dim3(256), 0, stream>>>(deg, incl, bsum, rowptr, cur, NN, EE);
  scatter_edges<<<dim3((EE + 255) / 256), dim3(256), 0, stream>>>(eidx, eattr, cur,
                                                                  srow, sea, EE);

  // h = x @ W_pre + b_pre  (via f16 split MFMA)
  split_f16<<<dim3((NN * 64 + 255) / 256), dim3(256), 0, stream>>>(x, x_hi, x_lo, NN);
  dim3 gg((NN + 127) / 128, 2);
  gemm_mfma<<<gg, dim3(256), 0, stream>>>(x_hi, x_lo, bt_hi, bt_lo, b_pre, h,
                                          (_Float16*)nullptr, NN);
  split_f16<<<dim3((NN * 64 + 255) / 256), dim3(256), 0, stream>>>(h, h_hi, h_lo, NN);
  hipMemsetAsync(msum, 0, (size_t)GG * DD * 4, stream);
  mean_accum<<<dim3(GG, 16), dim3(DD), 0, stream>>>(h, goff, msum);
  mean_fin<<<dim3(GG), dim3(DD), 0, stream>>>(msum, goff, hmean);

  for (int l = 0; l < LL; l++) {
    gemm_mfma<<<gg, dim3(256), 0, stream>>>(h_hi, h_lo,
                                            bt_hi + (size_t)(l + 1) * DD * DD,
                                            bt_lo + (size_t)(l + 1) * DD * DD,
                                            (const float*)nullptr, (float*)nullptr,
                                            xs16, NN);
    att_proj<<<dim3((NN + 31) / 32), dim3(256), 0, stream>>>(h, wmat + (size_t)l * DD * 8,
                                                             asrc, adst, NN);
    bool ws = (l < LL - 1);
    dst_fused<<<dim3((NN + 3) / 4), dim3(256), 0, stream>>>(
        xs16, asrc, adst, rowptr, srow, sea, wea + l * 8, bias_conv + l * DD,
        ln_g + l * DD, ln_b + l * DD, prelu + l * DD, h,
        ws ? h_hi : (_Float16*)nullptr, ws ? h_lo : (_Float16*)nullptr, NN);
    hipMemsetAsync(msum, 0, (size_t)GG * DD * 4, stream);
    mean_accum<<<dim3(GG, 16), dim3(DD), 0, stream>>>(h, goff, msum);
    mean_fin<<<dim3(GG), dim3(DD), 0, stream>>>(msum, goff,
                                                hmean + (size_t)(l + 1) * GG * DD);
  }

  head_mlp<<<dim3(GG), dim3(256), 0, stream>>>(hmean, W1, b1, W2, b2, Wr, br, out);
}